// Round 3
// baseline (1595.600 us; speedup 1.0000x reference)
//
#include <hip/hip_runtime.h>

#define NTOK   65536
#define NCODES 1024
#define DIM    128
#define BM     128          // tokens per block
#define BN     128          // codes per tile
#define NTILE  8            // 1024 / 128

typedef const __attribute__((address_space(1))) char gchar_t;
typedef __attribute__((address_space(3))) char lchar_t;

// ---------------- ee[c] = sum(embed[c,:]^2) in numpy pairwise (8-acc) order ----
__global__ __launch_bounds__(256) void ee_kernel(const float* __restrict__ E,
                                                 float* __restrict__ ee) {
  #pragma clang fp contract(off)
  int c = blockIdx.x * blockDim.x + threadIdx.x;
  if (c >= NCODES) return;
  const float4* r4 = (const float4*)(E + (size_t)c * DIM);
  float v[DIM];
  #pragma unroll
  for (int i = 0; i < 32; ++i) {
    float4 q = r4[i];
    v[4*i] = q.x; v[4*i+1] = q.y; v[4*i+2] = q.z; v[4*i+3] = q.w;
  }
  float r[8];
  #pragma unroll
  for (int j = 0; j < 8; ++j) r[j] = v[j] * v[j];
  #pragma unroll
  for (int i = 1; i < 16; ++i) {
    #pragma unroll
    for (int j = 0; j < 8; ++j) { float s = v[8*i+j] * v[8*i+j]; r[j] = r[j] + s; }
  }
  ee[c] = ((r[0]+r[1])+(r[2]+r[3])) + ((r[4]+r[5])+(r[6]+r[7]));
}

// ---------------- E_T[k4][c] = E[c][k4] (float4 granularity) ------------------
__global__ __launch_bounds__(256) void et_kernel(const float* __restrict__ E,
                                                 float* __restrict__ ET) {
  int id = blockIdx.x * 256 + threadIdx.x;   // 0..32767
  int c  = id & 1023;
  int k4 = id >> 10;
  ((float4*)ET)[id] = ((const float4*)E)[c * 32 + k4];   // writes coalesced
}

// ---------------- main: X-in-LDS register-blocked GEMM + argmin + epilogue ----
// 256 threads = (ty 0..15) x (tx 0..15); thread computes 8 tokens x 8 codes.
// X-tile (128 tokens x 128 k, 64KB) staged ONCE in LDS, XOR-swizzled so the
// 4-distinct-row broadcast reads hit 4 disjoint bank-quads. E read per-k4 from
// global (L2-resident, 512KB total) via transposed layout -> 256B contiguous
// per wave-load. No __syncthreads in the main loop.
__global__ __launch_bounds__(256, 2) void vq_main(
    const float* __restrict__ X, const float* __restrict__ E,
    const float* __restrict__ ET, const float* __restrict__ ee,
    float* __restrict__ out, float* __restrict__ counts,
    float* __restrict__ sums) {
  #pragma clang fp contract(off)
  __shared__ __align__(16) char x_lds[BM * 512];
  __shared__ int idx_s[BM];

  const int tid  = threadIdx.x;
  const int lane = tid & 63;
  const int wv   = tid >> 6;
  const int tx   = tid & 15;
  const int ty   = tid >> 4;
  const long blk = blockIdx.x;

  const float* Xb = X + (size_t)blk * BM * DIM;

  // ---- stage X block (64KB) via global_load_lds, pre-swizzled source -------
  #pragma unroll
  for (int q = 0; q < 16; ++q) {
    const int row = (wv * 16 + q) * 2 + (lane >> 5);
    const int k4l = lane & 31;
    const int k4g = k4l ^ ((row >> 3) & 7);           // swizzle low 3 bits
    gchar_t* src = (gchar_t*)((const char*)Xb + ((size_t)row << 9) + (k4g << 4));
    lchar_t* dst = (lchar_t*)(x_lds + (wv * 16 + q) * 1024);
    __builtin_amdgcn_global_load_lds((const __attribute__((address_space(1))) void*)src,
                                     (__attribute__((address_space(3))) void*)dst,
                                     16, 0, 0);
  }

  // ---- xx for my 8 tokens (numpy pairwise 8-acc order), from global --------
  float xx[8], best[8];
  int   bidx[8];
  #pragma unroll
  for (int i = 0; i < 8; ++i) {
    const float4* xr = (const float4*)(Xb + (ty * 8 + i) * DIM);
    float r[8];
    {
      float4 A = xr[0], B = xr[1];
      r[0]=A.x*A.x; r[1]=A.y*A.y; r[2]=A.z*A.z; r[3]=A.w*A.w;
      r[4]=B.x*B.x; r[5]=B.y*B.y; r[6]=B.z*B.z; r[7]=B.w*B.w;
    }
    #pragma unroll
    for (int g = 1; g < 16; ++g) {
      float4 A = xr[2*g], B = xr[2*g+1];
      float s0=A.x*A.x, s1=A.y*A.y, s2=A.z*A.z, s3=A.w*A.w;
      float s4=B.x*B.x, s5=B.y*B.y, s6=B.z*B.z, s7=B.w*B.w;
      r[0]=r[0]+s0; r[1]=r[1]+s1; r[2]=r[2]+s2; r[3]=r[3]+s3;
      r[4]=r[4]+s4; r[5]=r[5]+s5; r[6]=r[6]+s6; r[7]=r[7]+s7;
    }
    xx[i]   = ((r[0]+r[1])+(r[2]+r[3])) + ((r[4]+r[5])+(r[6]+r[7]));
    best[i] = __builtin_inff();
    bidx[i] = 0;
  }

  asm volatile("s_waitcnt vmcnt(0)" ::: "memory");
  __syncthreads();

  const int     tyw = ty & 7;
  const float4* xl  = (const float4*)x_lds;     // index: row*32 + k4phys
  const float4* eT0 = (const float4*)ET + tx;   // + k4*1024 + t*128 + 16*j

  for (int t = 0; t < NTILE; ++t) {
    float acc[8][8];
    #pragma unroll
    for (int i = 0; i < 8; ++i)
      #pragma unroll
      for (int j = 0; j < 8; ++j) acc[i][j] = 0.0f;

    const float4* eT = eT0 + t * BN;

    #pragma unroll 4
    for (int k4 = 0; k4 < 32; ++k4) {
      float4 ef[8], xf[8];
      #pragma unroll
      for (int j = 0; j < 8; ++j) ef[j] = eT[(k4 << 10) + 16 * j];
      const int k4p = k4 ^ tyw;
      #pragma unroll
      for (int i = 0; i < 8; ++i) xf[i] = xl[(ty * 8 + i) * 32 + k4p];
      #pragma unroll
      for (int i = 0; i < 8; ++i)
        #pragma unroll
        for (int j = 0; j < 8; ++j) {
          acc[i][j] = __builtin_fmaf(xf[i].x, ef[j].x, acc[i][j]);
          acc[i][j] = __builtin_fmaf(xf[i].y, ef[j].y, acc[i][j]);
          acc[i][j] = __builtin_fmaf(xf[i].z, ef[j].z, acc[i][j]);
          acc[i][j] = __builtin_fmaf(xf[i].w, ef[j].w, acc[i][j]);
        }
    }

    // ---- dist = (xx + ee) - 2*dot ; running argmin (strict <, ascending n) --
    float eev[8];
    #pragma unroll
    for (int j = 0; j < 8; ++j) eev[j] = ee[t * BN + tx + 16 * j];
    #pragma unroll
    for (int i = 0; i < 8; ++i)
      #pragma unroll
      for (int j = 0; j < 8; ++j) {
        float d = (xx[i] + eev[j]) - 2.0f * acc[i][j];
        int   n = t * BN + tx + 16 * j;
        if (d < best[i]) { best[i] = d; bidx[i] = n; }
      }
  }

  // ---- cross-tx butterfly reduce (lowest index wins on exact tie) ----------
  #pragma unroll
  for (int i = 0; i < 8; ++i) {
    float b = best[i]; int ix = bidx[i];
    #pragma unroll
    for (int m = 1; m < 16; m <<= 1) {
      float pb = __shfl_xor(b, m, 64);
      int   pi = __shfl_xor(ix, m, 64);
      if (pb < b || (pb == b && pi < ix)) { b = pb; ix = pi; }
    }
    if (tx == 0) idx_s[ty * 8 + i] = ix;
  }
  __syncthreads();

  // ---- epilogue: out = x + (e - x); segment atomics ------------------------
  const int   tt = tid >> 1;
  const int   hf = tid & 1;
  const int   fi = idx_s[tt];
  const float* xrow = Xb + tt * DIM + hf * 64;
  const float* erow = E + (size_t)fi * DIM + hf * 64;
  float*       orow = out + ((size_t)blk * BM + tt) * DIM + hf * 64;
  float*       srow = sums + (size_t)fi * DIM + hf * 64;
  #pragma unroll
  for (int q = 0; q < 16; ++q) {
    float4 xv = *(const float4*)(xrow + q * 4);
    float4 ev = *(const float4*)(erow + q * 4);
    float4 o;
    o.x = xv.x + (ev.x - xv.x);
    o.y = xv.y + (ev.y - xv.y);
    o.z = xv.z + (ev.z - xv.z);
    o.w = xv.w + (ev.w - xv.w);
    *(float4*)(orow + q * 4) = o;
    atomicAdd(srow + q * 4 + 0, xv.x);
    atomicAdd(srow + q * 4 + 1, xv.y);
    atomicAdd(srow + q * 4 + 2, xv.z);
    atomicAdd(srow + q * 4 + 3, xv.w);
  }
  if (hf == 0) atomicAdd(counts + fi, 1.0f);
}

// ---------------- finalize: EMA + cs + global sum ------------------------------
__global__ __launch_bounds__(1024) void finalize1(
    const float* __restrict__ cluster_size, const float* __restrict__ counts,
    float* __restrict__ out_cs, float* __restrict__ cs_ws) {
  #pragma clang fp contract(off)
  __shared__ float red[1024];
  const int n = threadIdx.x;
  float ncs = 0.99f * cluster_size[n] + 0.01f * counts[n];
  out_cs[n] = ncs;
  red[n] = ncs;
  __syncthreads();
  for (int s = 512; s > 0; s >>= 1) {
    if (n < s) red[n] = red[n] + red[n + s];
    __syncthreads();
  }
  float ntot = red[0];
  cs_ws[n] = (ncs + 1e-5f) / (ntot + 0.01024f) * ntot;
}

__global__ __launch_bounds__(256) void finalize2(
    const float* __restrict__ embed_avg, const float* __restrict__ sums,
    const float* __restrict__ cs_ws, float* __restrict__ out_embed,
    float* __restrict__ out_avg) {
  #pragma clang fp contract(off)
  int i = blockIdx.x * blockDim.x + threadIdx.x;
  float av = 0.99f * embed_avg[i] + 0.01f * sums[i];
  out_avg[i]   = av;
  out_embed[i] = av / cs_ws[i >> 7];
}

extern "C" void kernel_launch(void* const* d_in, const int* in_sizes, int n_in,
                              void* d_out, int out_size, void* d_ws, size_t ws_size,
                              hipStream_t stream) {
  const float* X  = (const float*)d_in[0];
  const float* E  = (const float*)d_in[1];
  const float* CS = (const float*)d_in[2];
  const float* EA = (const float*)d_in[3];
  float* out = (float*)d_out;
  float* ws  = (float*)d_ws;

  float* counts = ws;            // 1024
  float* sums   = ws + 1024;     // 131072
  float* eearr  = ws + 132096;   // 1024
  float* csarr  = ws + 133120;   // 1024
  float* etarr  = ws + 134144;   // 131072 (transposed E)

  // zero the atomic accumulators every call (ws is not re-poisoned between replays)
  hipMemsetAsync(d_ws, 0, (1024 + 131072) * sizeof(float), stream);

  ee_kernel<<<NCODES / 256, 256, 0, stream>>>(E, eearr);
  et_kernel<<<128, 256, 0, stream>>>(E, etarr);
  vq_main  <<<NTOK / BM, 256, 0, stream>>>(X, E, etarr, eearr, out, counts, sums);
  finalize1<<<1, 1024, 0, stream>>>(CS, counts, out + 8519680, csarr);
  finalize2<<<131072 / 256, 256, 0, stream>>>(EA, sums, csarr,
                                              out + 8388608, out + 8520704);
}

// Round 4
// 1512.989 us; speedup vs baseline: 1.0546x; 1.0546x over previous
//
#include <hip/hip_runtime.h>

#define NTOK   65536
#define NCODES 1024
#define DIM    128

// ---------------- ee[c] = sum(embed[c,:]^2) in numpy pairwise (8-acc) order ----
__global__ __launch_bounds__(256) void ee_kernel(const float* __restrict__ E,
                                                 float* __restrict__ ee) {
  #pragma clang fp contract(off)
  int c = blockIdx.x * blockDim.x + threadIdx.x;
  if (c >= NCODES) return;
  const float4* r4 = (const float4*)(E + (size_t)c * DIM);
  float v[DIM];
  #pragma unroll
  for (int i = 0; i < 32; ++i) {
    float4 q = r4[i];
    v[4*i] = q.x; v[4*i+1] = q.y; v[4*i+2] = q.z; v[4*i+3] = q.w;
  }
  float r[8];
  #pragma unroll
  for (int j = 0; j < 8; ++j) r[j] = v[j] * v[j];
  #pragma unroll
  for (int i = 1; i < 16; ++i) {
    #pragma unroll
    for (int j = 0; j < 8; ++j) { float s = v[8*i+j] * v[8*i+j]; r[j] = r[j] + s; }
  }
  ee[c] = ((r[0]+r[1])+(r[2]+r[3])) + ((r[4]+r[5])+(r[6]+r[7]));
}

// ---------------- main: thread=token, x in VGPRs, E via scalar loads ----------
// Block = 256 threads = 4 waves over the SAME 64 tokens (token = blk*64+lane).
// Wave wv sweeps codes [wv*256, wv*256+256): code index is wave-uniform, so
// E-row and ee loads scalarize to s_load (SMEM pipe) -> VALU does only FMAs.
// 4 interleaved fmaf chains hide dependent-FMA latency. No LDS in main loop.
__global__ __launch_bounds__(256, 3) void vq_main(
    const float* __restrict__ X, const float* __restrict__ E,
    const float* __restrict__ ee, float* __restrict__ out,
    float* __restrict__ counts, float* __restrict__ sums) {
  #pragma clang fp contract(off)
  __shared__ float bv_s[4][64];
  __shared__ int   bi_s[4][64];
  __shared__ int   idx_s[64];

  const int tid  = threadIdx.x;
  const int lane = tid & 63;
  const int wv   = __builtin_amdgcn_readfirstlane(tid >> 6);
  const long blk = blockIdx.x;
  const int  token = blk * 64 + lane;

  // ---- x row in registers (static indexing only) ---------------------------
  float x[DIM];
  {
    const float4* xr = (const float4*)(X + (size_t)token * DIM);
    #pragma unroll
    for (int i = 0; i < 32; ++i) {
      float4 v = xr[i];
      x[4*i] = v.x; x[4*i+1] = v.y; x[4*i+2] = v.z; x[4*i+3] = v.w;
    }
  }

  // ---- xx = sum(x^2) in numpy pairwise (8-acc) order -----------------------
  float xx;
  {
    float r[8];
    #pragma unroll
    for (int j = 0; j < 8; ++j) r[j] = x[j] * x[j];
    #pragma unroll
    for (int i = 1; i < 16; ++i) {
      #pragma unroll
      for (int j = 0; j < 8; ++j) { float s = x[8*i+j] * x[8*i+j]; r[j] = r[j] + s; }
    }
    xx = ((r[0]+r[1])+(r[2]+r[3])) + ((r[4]+r[5])+(r[6]+r[7]));
  }

  // ---- code sweep: 4 independent sequential-k fmaf chains per iteration ----
  float best = __builtin_inff();
  int   bidx = 0;
  const int n0 = wv * 256;
  for (int it = 0; it < 64; ++it) {
    const int n = n0 + it * 4;                       // wave-uniform
    const float* e0 = E + ((size_t)n << 7);
    const float* e1 = e0 + DIM;
    const float* e2 = e1 + DIM;
    const float* e3 = e2 + DIM;
    float d0 = 0.0f, d1 = 0.0f, d2 = 0.0f, d3 = 0.0f;
    #pragma unroll
    for (int k = 0; k < DIM; ++k) {
      d0 = __builtin_fmaf(x[k], e0[k], d0);
      d1 = __builtin_fmaf(x[k], e1[k], d1);
      d2 = __builtin_fmaf(x[k], e2[k], d2);
      d3 = __builtin_fmaf(x[k], e3[k], d3);
    }
    float t0 = (xx + ee[n + 0]) - 2.0f * d0;
    if (t0 < best) { best = t0; bidx = n; }
    float t1 = (xx + ee[n + 1]) - 2.0f * d1;
    if (t1 < best) { best = t1; bidx = n + 1; }
    float t2 = (xx + ee[n + 2]) - 2.0f * d2;
    if (t2 < best) { best = t2; bidx = n + 2; }
    float t3 = (xx + ee[n + 3]) - 2.0f * d3;
    if (t3 < best) { best = t3; bidx = n + 3; }
  }

  // ---- cross-wave merge (ascending wave = ascending code range) ------------
  bv_s[wv][lane] = best; bi_s[wv][lane] = bidx;
  __syncthreads();
  if (wv == 0) {
    float fb = bv_s[0][lane]; int fi = bi_s[0][lane];
    #pragma unroll
    for (int w = 1; w < 4; ++w) {
      float b = bv_s[w][lane]; int i2 = bi_s[w][lane];
      if (b < fb || (b == fb && i2 < fi)) { fb = b; fi = i2; }
    }
    idx_s[lane] = fi;
  }
  __syncthreads();

  // ---- epilogue: 4 threads/token, 32 dims each -----------------------------
  const int tq = tid >> 2;
  const int q  = tid & 3;
  const int fi = idx_s[tq];
  const float* xrow = X   + (((size_t)blk * 64 + tq) << 7) + q * 32;
  const float* erow = E   + ((size_t)fi << 7)              + q * 32;
  float*       orow = out + (((size_t)blk * 64 + tq) << 7) + q * 32;
  float*       srow = sums + ((size_t)fi << 7)             + q * 32;
  #pragma unroll
  for (int m = 0; m < 8; ++m) {
    float4 xv = *(const float4*)(xrow + 4 * m);
    float4 ev = *(const float4*)(erow + 4 * m);
    float4 o;
    o.x = xv.x + (ev.x - xv.x);
    o.y = xv.y + (ev.y - xv.y);
    o.z = xv.z + (ev.z - xv.z);
    o.w = xv.w + (ev.w - xv.w);
    *(float4*)(orow + 4 * m) = o;
    atomicAdd(srow + 4 * m + 0, xv.x);
    atomicAdd(srow + 4 * m + 1, xv.y);
    atomicAdd(srow + 4 * m + 2, xv.z);
    atomicAdd(srow + 4 * m + 3, xv.w);
  }
  if (q == 0) atomicAdd(counts + fi, 1.0f);
}

// ---------------- finalize: EMA + cs + global sum ------------------------------
__global__ __launch_bounds__(1024) void finalize1(
    const float* __restrict__ cluster_size, const float* __restrict__ counts,
    float* __restrict__ out_cs, float* __restrict__ cs_ws) {
  #pragma clang fp contract(off)
  __shared__ float red[1024];
  const int n = threadIdx.x;
  float ncs = 0.99f * cluster_size[n] + 0.01f * counts[n];
  out_cs[n] = ncs;
  red[n] = ncs;
  __syncthreads();
  for (int s = 512; s > 0; s >>= 1) {
    if (n < s) red[n] = red[n] + red[n + s];
    __syncthreads();
  }
  float ntot = red[0];
  cs_ws[n] = (ncs + 1e-5f) / (ntot + 0.01024f) * ntot;
}

__global__ __launch_bounds__(256) void finalize2(
    const float* __restrict__ embed_avg, const float* __restrict__ sums,
    const float* __restrict__ cs_ws, float* __restrict__ out_embed,
    float* __restrict__ out_avg) {
  #pragma clang fp contract(off)
  int i = blockIdx.x * blockDim.x + threadIdx.x;
  float av = 0.99f * embed_avg[i] + 0.01f * sums[i];
  out_avg[i]   = av;
  out_embed[i] = av / cs_ws[i >> 7];
}

extern "C" void kernel_launch(void* const* d_in, const int* in_sizes, int n_in,
                              void* d_out, int out_size, void* d_ws, size_t ws_size,
                              hipStream_t stream) {
  const float* X  = (const float*)d_in[0];
  const float* E  = (const float*)d_in[1];
  const float* CS = (const float*)d_in[2];
  const float* EA = (const float*)d_in[3];
  float* out = (float*)d_out;
  float* ws  = (float*)d_ws;

  float* counts = ws;            // 1024
  float* sums   = ws + 1024;     // 131072
  float* eearr  = ws + 132096;   // 1024
  float* csarr  = ws + 133120;   // 1024

  // zero the atomic accumulators every call (ws is not re-poisoned between replays)
  hipMemsetAsync(d_ws, 0, (1024 + 131072) * sizeof(float), stream);

  ee_kernel<<<NCODES / 256, 256, 0, stream>>>(E, eearr);
  vq_main  <<<NTOK / 64, 256, 0, stream>>>(X, E, eearr, out, counts, sums);
  finalize1<<<1, 1024, 0, stream>>>(CS, counts, out + 8519680, csarr);
  finalize2<<<131072 / 256, 256, 0, stream>>>(EA, sums, csarr,
                                              out + 8388608, out + 8520704);
}

// Round 5
// 550.485 us; speedup vs baseline: 2.8985x; 2.7485x over previous
//
#include <hip/hip_runtime.h>

#define NTOK   65536
#define NCODES 1024
#define DIM    128
#define BM     128          // tokens per block
#define BN     128          // codes per tile
#define NTILE  8            // 1024 / 128

typedef const __attribute__((address_space(1))) char gchar_t;
typedef __attribute__((address_space(3))) char lchar_t;

// ---------------- ee[c] = sum(embed[c,:]^2) in numpy pairwise (8-acc) order ----
__global__ __launch_bounds__(256) void ee_kernel(const float* __restrict__ E,
                                                 float* __restrict__ ee) {
  #pragma clang fp contract(off)
  int c = blockIdx.x * blockDim.x + threadIdx.x;
  if (c >= NCODES) return;
  const float4* r4 = (const float4*)(E + (size_t)c * DIM);
  float v[DIM];
  #pragma unroll
  for (int i = 0; i < 32; ++i) {
    float4 q = r4[i];
    v[4*i] = q.x; v[4*i+1] = q.y; v[4*i+2] = q.z; v[4*i+3] = q.w;
  }
  float r[8];
  #pragma unroll
  for (int j = 0; j < 8; ++j) r[j] = v[j] * v[j];
  #pragma unroll
  for (int i = 1; i < 16; ++i) {
    #pragma unroll
    for (int j = 0; j < 8; ++j) { float s = v[8*i+j] * v[8*i+j]; r[j] = r[j] + s; }
  }
  ee[c] = ((r[0]+r[1])+(r[2]+r[3])) + ((r[4]+r[5])+(r[6]+r[7]));
}

// ---------------- main: X-LDS + E-LDS register-blocked GEMM + argmin ----------
// 256 threads = (ty 0..15) x (tx 0..15); thread computes 8 tokens x 8 codes.
// X staged once (swizzle: k4 ^ (row>>3)&7, read proven conflict-free in r3);
// E-tile staged per t (swizzle: k4 ^ (row>>3)&15, proven conflict-free in r2).
// k-loop touches ONLY LDS. Epilogue: out + idx writes, NO atomics.
__global__ __launch_bounds__(256, 1) void vq_main(
    const float* __restrict__ X, const float* __restrict__ E,
    const float* __restrict__ ee, float* __restrict__ out,
    int* __restrict__ idxg) {
  #pragma clang fp contract(off)
  __shared__ __align__(16) char x_lds[BM * 512];
  __shared__ __align__(16) char e_lds[BN * 512];
  __shared__ int idx_s[BM];

  const int tid  = threadIdx.x;
  const int lane = tid & 63;
  const int wv   = tid >> 6;
  const int tx   = tid & 15;
  const int ty   = tid >> 4;
  const long blk = blockIdx.x;

  const float* Xb = X + (size_t)blk * BM * DIM;

  // ---- stage X block (64KB) once, pre-swizzled source ----------------------
  #pragma unroll
  for (int q = 0; q < 16; ++q) {
    const int row = (wv * 16 + q) * 2 + (lane >> 5);
    const int k4l = lane & 31;
    const int k4g = k4l ^ ((row >> 3) & 7);
    gchar_t* src = (gchar_t*)((const char*)Xb + ((size_t)row << 9) + (k4g << 4));
    lchar_t* dst = (lchar_t*)(x_lds + (wv * 16 + q) * 1024);
    __builtin_amdgcn_global_load_lds((const __attribute__((address_space(1))) void*)src,
                                     (__attribute__((address_space(3))) void*)dst,
                                     16, 0, 0);
  }

  // ---- xx for my 8 tokens (numpy pairwise 8-acc order), from global --------
  float xx[8], best[8];
  int   bidx[8];
  #pragma unroll
  for (int i = 0; i < 8; ++i) {
    const float4* xr = (const float4*)(Xb + (ty * 8 + i) * DIM);
    float r[8];
    {
      float4 A = xr[0], B = xr[1];
      r[0]=A.x*A.x; r[1]=A.y*A.y; r[2]=A.z*A.z; r[3]=A.w*A.w;
      r[4]=B.x*B.x; r[5]=B.y*B.y; r[6]=B.z*B.z; r[7]=B.w*B.w;
    }
    #pragma unroll
    for (int g = 1; g < 16; ++g) {
      float4 A = xr[2*g], B = xr[2*g+1];
      float s0=A.x*A.x, s1=A.y*A.y, s2=A.z*A.z, s3=A.w*A.w;
      float s4=B.x*B.x, s5=B.y*B.y, s6=B.z*B.z, s7=B.w*B.w;
      r[0]=r[0]+s0; r[1]=r[1]+s1; r[2]=r[2]+s2; r[3]=r[3]+s3;
      r[4]=r[4]+s4; r[5]=r[5]+s5; r[6]=r[6]+s6; r[7]=r[7]+s7;
    }
    xx[i]   = ((r[0]+r[1])+(r[2]+r[3])) + ((r[4]+r[5])+(r[6]+r[7]));
    best[i] = __builtin_inff();
    bidx[i] = 0;
  }

  const int     tyw = ty & 7;
  const float4* xl  = (const float4*)x_lds;

  for (int t = 0; t < NTILE; ++t) {
    __syncthreads();   // previous tile fully consumed (t=0: nothing read yet)
    // ---- stage e-tile t (64KB), pre-swizzled source ------------------------
    #pragma unroll
    for (int q = 0; q < 16; ++q) {
      const int row = (wv * 16 + q) * 2 + (lane >> 5);
      const int k4l = lane & 31;
      const int k4g = k4l ^ ((row >> 3) & 15);
      gchar_t* src = (gchar_t*)((const char*)E
                      + ((size_t)(t * BN + row) << 9) + (k4g << 4));
      lchar_t* dst = (lchar_t*)(e_lds + (wv * 16 + q) * 1024);
      __builtin_amdgcn_global_load_lds((const __attribute__((address_space(1))) void*)src,
                                       (__attribute__((address_space(3))) void*)dst,
                                       16, 0, 0);
    }
    asm volatile("s_waitcnt vmcnt(0)" ::: "memory");
    __syncthreads();

    // ---- k-sweep: acc[8][8], sequential-k fmaf chains (bit-exact order) ----
    float acc[8][8];
    #pragma unroll
    for (int i = 0; i < 8; ++i)
      #pragma unroll
      for (int j = 0; j < 8; ++j) acc[i][j] = 0.0f;

    #pragma unroll 2
    for (int k4 = 0; k4 < 32; ++k4) {
      float4 xf[8], ef[8];
      const int k4p = k4 ^ tyw;
      #pragma unroll
      for (int i = 0; i < 8; ++i) xf[i] = xl[(ty * 8 + i) * 32 + k4p];
      #pragma unroll
      for (int j = 0; j < 8; ++j) {
        const int r = tx * 8 + j;             // r>>3 == tx
        ef[j] = *(const float4*)(e_lds + r * 512 + (((k4 ^ tx) & 31) << 4));
      }
      #pragma unroll
      for (int i = 0; i < 8; ++i)
        #pragma unroll
        for (int j = 0; j < 8; ++j) {
          acc[i][j] = __builtin_fmaf(xf[i].x, ef[j].x, acc[i][j]);
          acc[i][j] = __builtin_fmaf(xf[i].y, ef[j].y, acc[i][j]);
          acc[i][j] = __builtin_fmaf(xf[i].z, ef[j].z, acc[i][j]);
          acc[i][j] = __builtin_fmaf(xf[i].w, ef[j].w, acc[i][j]);
        }
    }

    // ---- dist = (xx + ee) - 2*dot ; running argmin (strict <, ascending n) --
    const float4* ee4 = (const float4*)(ee + t * BN + tx * 8);
    float4 eeA = ee4[0], eeB = ee4[1];
    float eev[8] = {eeA.x, eeA.y, eeA.z, eeA.w, eeB.x, eeB.y, eeB.z, eeB.w};
    #pragma unroll
    for (int i = 0; i < 8; ++i)
      #pragma unroll
      for (int j = 0; j < 8; ++j) {
        float d = (xx[i] + eev[j]) - 2.0f * acc[i][j];
        int   n = t * BN + tx * 8 + j;
        if (d < best[i]) { best[i] = d; bidx[i] = n; }
      }
  }

  // ---- cross-tx butterfly reduce (lowest index wins on exact tie) ----------
  #pragma unroll
  for (int i = 0; i < 8; ++i) {
    float b = best[i]; int ix = bidx[i];
    #pragma unroll
    for (int m = 1; m < 16; m <<= 1) {
      float pb = __shfl_xor(b, m, 64);
      int   pi = __shfl_xor(ix, m, 64);
      if (pb < b || (pb == b && pi < ix)) { b = pb; ix = pi; }
    }
    if (tx == 0) idx_s[ty * 8 + i] = ix;
  }
  __syncthreads();

  // ---- epilogue: out = x + (e - x); idx write; NO atomics ------------------
  const int   tt = tid >> 1;
  const int   hf = tid & 1;
  const int   fi = idx_s[tt];
  const float* xrow = Xb  + tt * DIM + hf * 64;
  const float* erow = E   + ((size_t)fi << 7) + hf * 64;
  float*       orow = out + ((size_t)blk * BM + tt) * DIM + hf * 64;
  #pragma unroll
  for (int q = 0; q < 16; ++q) {
    float4 xv = *(const float4*)(xrow + q * 4);
    float4 ev = *(const float4*)(erow + q * 4);
    float4 o;
    o.x = xv.x + (ev.x - xv.x);
    o.y = xv.y + (ev.y - xv.y);
    o.z = xv.z + (ev.z - xv.z);
    o.w = xv.w + (ev.w - xv.w);
    *(float4*)(orow + q * 4) = o;
  }
  if (hf == 0) idxg[blk * BM + tt] = fi;
}

// ---------------- counts + sums by scanning idx (no atomics) ------------------
// One block per code c. Each wave scans 64 tokens/iter via ballot compaction;
// matching token rows accumulated into wave-private float2 regs (order-free:
// prior rounds passed with random atomic order).
__global__ __launch_bounds__(256) void sums_kernel(
    const float* __restrict__ X, const int* __restrict__ idx,
    float* __restrict__ counts, float* __restrict__ sums) {
  #pragma clang fp contract(off)
  const int c    = blockIdx.x;
  const int tid  = threadIdx.x;
  const int lane = tid & 63;
  const int wv   = tid >> 6;
  float ax = 0.0f, ay = 0.0f;
  int cnt = 0;
  for (int base = 0; base < NTOK; base += 256) {
    int v = idx[base + tid];
    unsigned long long m = __ballot(v == c);
    cnt += (int)__popcll(m);
    while (m) {
      int b = (int)__builtin_ctzll(m);
      m &= m - 1;
      int token = base + wv * 64 + b;
      float2 xv = *((const float2*)(X + ((size_t)token << 7)) + lane);
      ax = ax + xv.x;
      ay = ay + xv.y;
    }
  }
  __shared__ float accs[4][DIM];
  __shared__ int   cnts[4];
  accs[wv][lane * 2]     = ax;
  accs[wv][lane * 2 + 1] = ay;
  if (lane == 0) cnts[wv] = cnt;
  __syncthreads();
  if (wv == 0) {
    float sx = ((accs[0][lane*2]   + accs[1][lane*2])
              + (accs[2][lane*2]   + accs[3][lane*2]));
    float sy = ((accs[0][lane*2+1] + accs[1][lane*2+1])
              + (accs[2][lane*2+1] + accs[3][lane*2+1]));
    sums[c * DIM + lane*2]     = sx;
    sums[c * DIM + lane*2 + 1] = sy;
    if (lane == 0) counts[c] = (float)((cnts[0] + cnts[1]) + (cnts[2] + cnts[3]));
  }
}

// ---------------- finalize: EMA + cs + global sum ------------------------------
__global__ __launch_bounds__(1024) void finalize1(
    const float* __restrict__ cluster_size, const float* __restrict__ counts,
    float* __restrict__ out_cs, float* __restrict__ cs_ws) {
  #pragma clang fp contract(off)
  __shared__ float red[1024];
  const int n = threadIdx.x;
  float ncs = 0.99f * cluster_size[n] + 0.01f * counts[n];
  out_cs[n] = ncs;
  red[n] = ncs;
  __syncthreads();
  for (int s = 512; s > 0; s >>= 1) {
    if (n < s) red[n] = red[n] + red[n + s];
    __syncthreads();
  }
  float ntot = red[0];
  cs_ws[n] = (ncs + 1e-5f) / (ntot + 0.01024f) * ntot;
}

__global__ __launch_bounds__(256) void finalize2(
    const float* __restrict__ embed_avg, const float* __restrict__ sums,
    const float* __restrict__ cs_ws, float* __restrict__ out_embed,
    float* __restrict__ out_avg) {
  #pragma clang fp contract(off)
  int i = blockIdx.x * blockDim.x + threadIdx.x;
  float av = 0.99f * embed_avg[i] + 0.01f * sums[i];
  out_avg[i]   = av;
  out_embed[i] = av / cs_ws[i >> 7];
}

extern "C" void kernel_launch(void* const* d_in, const int* in_sizes, int n_in,
                              void* d_out, int out_size, void* d_ws, size_t ws_size,
                              hipStream_t stream) {
  const float* X  = (const float*)d_in[0];
  const float* E  = (const float*)d_in[1];
  const float* CS = (const float*)d_in[2];
  const float* EA = (const float*)d_in[3];
  float* out = (float*)d_out;
  float* ws  = (float*)d_ws;

  float* counts = ws;            // 1024
  float* sums   = ws + 1024;     // 131072
  float* eearr  = ws + 132096;   // 1024
  float* csarr  = ws + 133120;   // 1024
  int*   idxarr = (int*)(ws + 134144);  // 65536 ints

  ee_kernel  <<<NCODES / 256, 256, 0, stream>>>(E, eearr);
  vq_main    <<<NTOK / BM,    256, 0, stream>>>(X, E, eearr, out, idxarr);
  sums_kernel<<<NCODES,       256, 0, stream>>>(X, idxarr, counts, sums);
  finalize1  <<<1, 1024, 0, stream>>>(CS, counts, out + 8519680, csarr);
  finalize2  <<<131072 / 256, 256, 0, stream>>>(EA, sums, csarr,
                                                out + 8388608, out + 8520704);
}

// Round 6
// 495.742 us; speedup vs baseline: 3.2186x; 1.1104x over previous
//
#include <hip/hip_runtime.h>

#define NTOK   65536
#define NCODES 1024
#define DIM    128
#define BM     128          // tokens per block
#define BN     128          // codes per tile
#define NT     8            // 1024 / 128

typedef const __attribute__((address_space(1))) char gchar_t;
typedef __attribute__((address_space(3))) char lchar_t;

// ---------------- ee[c] = sum(embed[c,:]^2) in numpy pairwise (8-acc) order ----
__global__ __launch_bounds__(256) void ee_kernel(const float* __restrict__ E,
                                                 float* __restrict__ ee) {
  #pragma clang fp contract(off)
  int c = blockIdx.x * blockDim.x + threadIdx.x;
  if (c >= NCODES) return;
  const float4* r4 = (const float4*)(E + (size_t)c * DIM);
  float v[DIM];
  #pragma unroll
  for (int i = 0; i < 32; ++i) {
    float4 q = r4[i];
    v[4*i] = q.x; v[4*i+1] = q.y; v[4*i+2] = q.z; v[4*i+3] = q.w;
  }
  float r[8];
  #pragma unroll
  for (int j = 0; j < 8; ++j) r[j] = v[j] * v[j];
  #pragma unroll
  for (int i = 1; i < 16; ++i) {
    #pragma unroll
    for (int j = 0; j < 8; ++j) { float s = v[8*i+j] * v[8*i+j]; r[j] = r[j] + s; }
  }
  ee[c] = ((r[0]+r[1])+(r[2]+r[3])) + ((r[4]+r[5])+(r[6]+r[7]));
}

// ---------------- main: X-LDS + double-buffered 32KB E-chunks, pipelined ------
// 256 threads = (ty 0..15) x (tx 0..15); thread computes 8 tokens x 8 codes.
// X staged once (swizzle k4 ^ ty&7, conflict-free, proven r3/r5). E staged in
// 32KB half-k chunks, double-buffered; next chunk's global_load_lds issued
// BEFORE computing the current chunk -> L2 latency hides under 8192cy of FMA.
// Chunk layout: row-stride 256B, slot k4l holds global k-quad (k4l^tx)&15
// -> ds_read addr (tx*8+j)*256 + ((kk^tx)&15)*16 is conflict-free.
__global__ __launch_bounds__(256, 1) void vq_main(
    const float* __restrict__ X, const float* __restrict__ E,
    const float* __restrict__ ee, float* __restrict__ out,
    int* __restrict__ idxg, int* __restrict__ cnt_i) {
  #pragma clang fp contract(off)
  __shared__ __align__(16) char x_lds[BM * 512];
  __shared__ __align__(16) char e_lds[2 * BN * 256];
  __shared__ int idx_s[BM];

  const int tid  = threadIdx.x;
  const int lane = tid & 63;
  const int wv   = tid >> 6;
  const int tx   = tid & 15;
  const int ty   = tid >> 4;
  const long blk = blockIdx.x;

  const float* Xb = X + (size_t)blk * BM * DIM;

  // ---- stage X block (64KB) once, pre-swizzled source ----------------------
  #pragma unroll
  for (int q = 0; q < 16; ++q) {
    const int row = (wv * 16 + q) * 2 + (lane >> 5);
    const int k4l = lane & 31;
    const int k4g = k4l ^ ((row >> 3) & 7);
    gchar_t* src = (gchar_t*)((const char*)Xb + ((size_t)row << 9) + (k4g << 4));
    lchar_t* dst = (lchar_t*)(x_lds + (wv * 16 + q) * 1024);
    __builtin_amdgcn_global_load_lds((const __attribute__((address_space(1))) void*)src,
                                     (__attribute__((address_space(3))) void*)dst,
                                     16, 0, 0);
  }

  // ---- stage E chunk (t, kh) into BASE: 32KB = 128 rows x 256B -------------
#define STAGE_E(T, KH, BASE)                                                  \
  {                                                                           \
    _Pragma("unroll")                                                         \
    for (int q = 0; q < 8; ++q) {                                             \
      const int row = (wv * 8 + q) * 4 + (lane >> 4);                         \
      const int k4l = lane & 15;                                              \
      const int k4g = (k4l ^ (row >> 3)) & 15;                                \
      gchar_t* src = (gchar_t*)((const char*)E                                \
          + ((size_t)((T) * BN + row) << 9) + ((KH) << 8) + (k4g << 4));      \
      lchar_t* dst = (lchar_t*)((BASE) + (wv * 8 + q) * 1024);                \
      __builtin_amdgcn_global_load_lds(                                       \
          (const __attribute__((address_space(1))) void*)src,                 \
          (__attribute__((address_space(3))) void*)dst, 16, 0, 0);            \
    }                                                                         \
  }

  STAGE_E(0, 0, e_lds)

  // ---- xx for my 8 tokens (numpy pairwise 8-acc order), from global --------
  float xx[8], best[8];
  int   bidx[8];
  #pragma unroll
  for (int i = 0; i < 8; ++i) {
    const float4* xr = (const float4*)(Xb + (ty * 8 + i) * DIM);
    float r[8];
    {
      float4 A = xr[0], B = xr[1];
      r[0]=A.x*A.x; r[1]=A.y*A.y; r[2]=A.z*A.z; r[3]=A.w*A.w;
      r[4]=B.x*B.x; r[5]=B.y*B.y; r[6]=B.z*B.z; r[7]=B.w*B.w;
    }
    #pragma unroll
    for (int g = 1; g < 16; ++g) {
      float4 A = xr[2*g], B = xr[2*g+1];
      float s0=A.x*A.x, s1=A.y*A.y, s2=A.z*A.z, s3=A.w*A.w;
      float s4=B.x*B.x, s5=B.y*B.y, s6=B.z*B.z, s7=B.w*B.w;
      r[0]=r[0]+s0; r[1]=r[1]+s1; r[2]=r[2]+s2; r[3]=r[3]+s3;
      r[4]=r[4]+s4; r[5]=r[5]+s5; r[6]=r[6]+s6; r[7]=r[7]+s7;
    }
    xx[i]   = ((r[0]+r[1])+(r[2]+r[3])) + ((r[4]+r[5])+(r[6]+r[7]));
    best[i] = __builtin_inff();
    bidx[i] = 0;
  }

  asm volatile("s_waitcnt vmcnt(0)" ::: "memory");
  __syncthreads();

  const int     tyw = ty & 7;
  const float4* xl  = (const float4*)x_lds;

  float acc[8][8];

  // kk-sweep over one 16-k4 chunk; k4 global = KH*16+kk; sequential-k fmaf
#define KSWEEP(BASE, KH)                                                      \
  {                                                                           \
    _Pragma("unroll 2")                                                       \
    for (int kk = 0; kk < 16; ++kk) {                                         \
      float4 xf[8], ef[8];                                                    \
      const int k4p = ((KH) * 16 + kk) ^ tyw;                                 \
      _Pragma("unroll")                                                       \
      for (int i = 0; i < 8; ++i) xf[i] = xl[(ty * 8 + i) * 32 + k4p];        \
      _Pragma("unroll")                                                       \
      for (int j = 0; j < 8; ++j)                                             \
        ef[j] = *(const float4*)((BASE) + (tx * 8 + j) * 256                  \
                                 + (((kk ^ tx) & 15) << 4));                  \
      _Pragma("unroll")                                                       \
      for (int i = 0; i < 8; ++i)                                             \
        _Pragma("unroll")                                                     \
        for (int j = 0; j < 8; ++j) {                                         \
          acc[i][j] = __builtin_fmaf(xf[i].x, ef[j].x, acc[i][j]);            \
          acc[i][j] = __builtin_fmaf(xf[i].y, ef[j].y, acc[i][j]);            \
          acc[i][j] = __builtin_fmaf(xf[i].z, ef[j].z, acc[i][j]);            \
          acc[i][j] = __builtin_fmaf(xf[i].w, ef[j].w, acc[i][j]);            \
        }                                                                     \
    }                                                                         \
  }

  for (int t = 0; t < NT; ++t) {
    // buffers at entry: buf0 = chunk (t,0) ready; issue (t,1) then compute.
    STAGE_E(t, 1, e_lds + 32768)
    #pragma unroll
    for (int i = 0; i < 8; ++i)
      #pragma unroll
      for (int j = 0; j < 8; ++j) acc[i][j] = 0.0f;
    KSWEEP(e_lds, 0)
    asm volatile("s_waitcnt vmcnt(0)" ::: "memory");
    __syncthreads();
    if (t < NT - 1) STAGE_E(t + 1, 0, e_lds)
    KSWEEP(e_lds + 32768, 1)

    // ---- dist = (xx + ee) - 2*dot ; running argmin (strict <, ascending n) --
    const float4* ee4 = (const float4*)(ee + t * BN + tx * 8);
    float4 eeA = ee4[0], eeB = ee4[1];
    float eev[8] = {eeA.x, eeA.y, eeA.z, eeA.w, eeB.x, eeB.y, eeB.z, eeB.w};
    #pragma unroll
    for (int i = 0; i < 8; ++i)
      #pragma unroll
      for (int j = 0; j < 8; ++j) {
        float d = (xx[i] + eev[j]) - 2.0f * acc[i][j];
        int   n = t * BN + tx * 8 + j;
        if (d < best[i]) { best[i] = d; bidx[i] = n; }
      }
    asm volatile("s_waitcnt vmcnt(0)" ::: "memory");
    __syncthreads();
  }

  // ---- cross-tx butterfly reduce (lowest index wins on exact tie) ----------
  #pragma unroll
  for (int i = 0; i < 8; ++i) {
    float b = best[i]; int ix = bidx[i];
    #pragma unroll
    for (int m = 1; m < 16; m <<= 1) {
      float pb = __shfl_xor(b, m, 64);
      int   pi = __shfl_xor(ix, m, 64);
      if (pb < b || (pb == b && pi < ix)) { b = pb; ix = pi; }
    }
    if (tx == 0) idx_s[ty * 8 + i] = ix;
  }
  __syncthreads();

  // ---- epilogue: out = x + (e - x); idx + histogram ------------------------
  const int   tt = tid >> 1;
  const int   hf = tid & 1;
  const int   fi = idx_s[tt];
  const float* xrow = Xb  + tt * DIM + hf * 64;
  const float* erow = E   + ((size_t)fi << 7) + hf * 64;
  float*       orow = out + ((size_t)blk * BM + tt) * DIM + hf * 64;
  #pragma unroll
  for (int q = 0; q < 16; ++q) {
    float4 xv = *(const float4*)(xrow + q * 4);
    float4 ev = *(const float4*)(erow + q * 4);
    float4 o;
    o.x = xv.x + (ev.x - xv.x);
    o.y = xv.y + (ev.y - xv.y);
    o.z = xv.z + (ev.z - xv.z);
    o.w = xv.w + (ev.w - xv.w);
    *(float4*)(orow + q * 4) = o;
  }
  if (hf == 0) {
    idxg[blk * BM + tt] = fi;
    atomicAdd(cnt_i + fi, 1);
  }
}

// ---------------- prefix + finalize1: cs outputs, cs_ws, CSR offsets ----------
__global__ __launch_bounds__(1024) void prefix_fin1(
    const float* __restrict__ cluster_size, const int* __restrict__ cnt_i,
    float* __restrict__ out_cs, float* __restrict__ cs_ws,
    int* __restrict__ cursor, int* __restrict__ offs) {
  #pragma clang fp contract(off)
  __shared__ float red[1024];
  __shared__ int   sc[1024];
  const int n = threadIdx.x;
  const int cnt = cnt_i[n];
  float ncs = 0.99f * cluster_size[n] + 0.01f * (float)cnt;
  out_cs[n] = ncs;
  red[n] = ncs;
  sc[n]  = cnt;
  __syncthreads();
  // sum reduction (same tree as rounds 1-5, passing)
  for (int s = 512; s > 0; s >>= 1) {
    if (n < s) red[n] = red[n] + red[n + s];
    __syncthreads();
  }
  float ntot = red[0];
  cs_ws[n] = (ncs + 1e-5f) / (ntot + 0.01024f) * ntot;
  // Hillis-Steele inclusive scan -> exclusive offsets
  for (int d = 1; d < 1024; d <<= 1) {
    int t = (n >= d) ? sc[n - d] : 0;
    __syncthreads();
    sc[n] += t;
    __syncthreads();
  }
  int excl = sc[n] - cnt;
  cursor[n] = excl;
  offs[n]   = excl;
}

// ---------------- scatter tokens into CSR order -------------------------------
__global__ __launch_bounds__(256) void scatter_kernel(
    const int* __restrict__ idxg, int* __restrict__ cursor,
    int* __restrict__ order) {
  const int t  = blockIdx.x * 256 + threadIdx.x;
  const int fi = idxg[t];
  const int slot = atomicAdd(cursor + fi, 1);
  order[slot] = t;
}

// ---------------- per-code sums + finalize2 (fused) ---------------------------
// Block c: gather its token rows (coalesced 64-lane float2 = full 512B row),
// reduce across 4 waves in LDS, then EMA + divide, write embed/avg rows.
__global__ __launch_bounds__(256) void sums_fin2(
    const float* __restrict__ X, const int* __restrict__ order,
    const int* __restrict__ offs, const int* __restrict__ cnt_i,
    const float* __restrict__ embed_avg, const float* __restrict__ cs_ws,
    float* __restrict__ out_embed, float* __restrict__ out_avg) {
  #pragma clang fp contract(off)
  __shared__ float accs[4][DIM];
  const int c     = blockIdx.x;
  const int lane  = threadIdx.x & 63;
  const int wv    = threadIdx.x >> 6;
  const int start = offs[c];
  const int num   = cnt_i[c];
  float ax0 = 0.0f, ay0 = 0.0f, ax1 = 0.0f, ay1 = 0.0f;
  int u = wv;
  for (; u + 4 < num; u += 8) {
    int t0 = order[start + u];
    int t1 = order[start + u + 4];
    float2 a = *((const float2*)(X + ((size_t)t0 << 7)) + lane);
    float2 b = *((const float2*)(X + ((size_t)t1 << 7)) + lane);
    ax0 = ax0 + a.x; ay0 = ay0 + a.y;
    ax1 = ax1 + b.x; ay1 = ay1 + b.y;
  }
  if (u < num) {
    int t0 = order[start + u];
    float2 a = *((const float2*)(X + ((size_t)t0 << 7)) + lane);
    ax0 = ax0 + a.x; ay0 = ay0 + a.y;
  }
  accs[wv][lane * 2]     = ax0 + ax1;
  accs[wv][lane * 2 + 1] = ay0 + ay1;
  __syncthreads();
  if (wv == 0) {
    float sx = (accs[0][lane*2]   + accs[1][lane*2])
             + (accs[2][lane*2]   + accs[3][lane*2]);
    float sy = (accs[0][lane*2+1] + accs[1][lane*2+1])
             + (accs[2][lane*2+1] + accs[3][lane*2+1]);
    float avx = 0.99f * embed_avg[c * DIM + lane*2]     + 0.01f * sx;
    float avy = 0.99f * embed_avg[c * DIM + lane*2 + 1] + 0.01f * sy;
    float cs  = cs_ws[c];
    out_avg[c * DIM + lane*2]       = avx;
    out_avg[c * DIM + lane*2 + 1]   = avy;
    out_embed[c * DIM + lane*2]     = avx / cs;
    out_embed[c * DIM + lane*2 + 1] = avy / cs;
  }
}

extern "C" void kernel_launch(void* const* d_in, const int* in_sizes, int n_in,
                              void* d_out, int out_size, void* d_ws, size_t ws_size,
                              hipStream_t stream) {
  const float* X  = (const float*)d_in[0];
  const float* E  = (const float*)d_in[1];
  const float* CS = (const float*)d_in[2];
  const float* EA = (const float*)d_in[3];
  float* out = (float*)d_out;
  float* ws  = (float*)d_ws;

  float* eearr  = ws;                       // 1024 f
  float* csarr  = ws + 1024;                // 1024 f
  int*   cnt_i  = (int*)(ws + 2048);        // 1024 i
  int*   cursor = (int*)(ws + 3072);        // 1024 i
  int*   offs   = (int*)(ws + 4096);        // 1024 i
  int*   idxarr = (int*)(ws + 5120);        // 65536 i
  int*   order  = (int*)(ws + 70656);       // 65536 i

  hipMemsetAsync(cnt_i, 0, NCODES * sizeof(int), stream);

  ee_kernel     <<<NCODES / 256, 256, 0, stream>>>(E, eearr);
  vq_main       <<<NTOK / BM,    256, 0, stream>>>(X, E, eearr, out, idxarr, cnt_i);
  prefix_fin1   <<<1, 1024, 0, stream>>>(CS, cnt_i, out + 8519680, csarr,
                                         cursor, offs);
  scatter_kernel<<<NTOK / 256,   256, 0, stream>>>(idxarr, cursor, order);
  sums_fin2     <<<NCODES,       256, 0, stream>>>(X, order, offs, cnt_i, EA,
                                                   csarr, out + 8388608,
                                                   out + 8520704);
}

// Round 7
// 455.193 us; speedup vs baseline: 3.5053x; 1.0891x over previous
//
#include <hip/hip_runtime.h>

#define NTOK   65536
#define NCODES 1024
#define DIM    128
#define BM     256          // tokens per block
#define BN     128          // codes per tile
#define NT     8            // 1024 / 128

typedef const __attribute__((address_space(1))) char gchar_t;
typedef __attribute__((address_space(3))) char lchar_t;

// ---------------- ee[c] = sum(embed[c,:]^2) in numpy pairwise (8-acc) order ----
__global__ __launch_bounds__(256) void ee_kernel(const float* __restrict__ E,
                                                 float* __restrict__ ee) {
  #pragma clang fp contract(off)
  int c = blockIdx.x * blockDim.x + threadIdx.x;
  if (c >= NCODES) return;
  const float4* r4 = (const float4*)(E + (size_t)c * DIM);
  float v[DIM];
  #pragma unroll
  for (int i = 0; i < 32; ++i) {
    float4 q = r4[i];
    v[4*i] = q.x; v[4*i+1] = q.y; v[4*i+2] = q.z; v[4*i+3] = q.w;
  }
  float r[8];
  #pragma unroll
  for (int j = 0; j < 8; ++j) r[j] = v[j] * v[j];
  #pragma unroll
  for (int i = 1; i < 16; ++i) {
    #pragma unroll
    for (int j = 0; j < 8; ++j) { float s = v[8*i+j] * v[8*i+j]; r[j] = r[j] + s; }
  }
  ee[c] = ((r[0]+r[1])+(r[2]+r[3])) + ((r[4]+r[5])+(r[6]+r[7]));
}

// ---------------- main: 512-thread block, X 128KB LDS, 16KB E-chunks ----------
// 512 threads = (ty 0..31) x (tx 0..15); thread computes 8 tokens x 8 codes.
// 1 block/CU but 8 waves -> 2 waves/SIMD (TLP hides LDS latency; r6 had 1).
// X staged once, swizzle slot = k4 ^ (row>>3)&7 (xf: 4 disjoint bank-quads).
// E chunk = 128 codes x 8 k-quads (16KB), slot = (k4 ^ row>>3)&7 (ef: 2-way,
// free per m136). idx_s aliases x_lds after the k-loop.
__global__ __launch_bounds__(512, 2) void vq_main(
    const float* __restrict__ X, const float* __restrict__ E,
    const float* __restrict__ ee, float* __restrict__ out,
    int* __restrict__ idxg, int* __restrict__ cnt_i) {
  #pragma clang fp contract(off)
  __shared__ __align__(16) char x_lds[BM * 512];   // 128 KB
  __shared__ __align__(16) char e_lds[BN * 128];   // 16 KB

  const int tid  = threadIdx.x;
  const int lane = tid & 63;
  const int wv   = tid >> 6;
  const int tx   = tid & 15;
  const int ty   = tid >> 4;
  const long blk = blockIdx.x;

  const float* Xb = X + (size_t)blk * BM * DIM;

  // ---- stage X block (128KB) once, pre-swizzled source ---------------------
  #pragma unroll
  for (int q = 0; q < 16; ++q) {
    const int row = (wv * 16 + q) * 2 + (lane >> 5);
    const int k4l = lane & 31;
    const int k4g = k4l ^ ((row >> 3) & 7);
    gchar_t* src = (gchar_t*)((const char*)Xb + ((size_t)row << 9) + (k4g << 4));
    lchar_t* dst = (lchar_t*)(x_lds + (wv * 16 + q) * 1024);
    __builtin_amdgcn_global_load_lds((const __attribute__((address_space(1))) void*)src,
                                     (__attribute__((address_space(3))) void*)dst,
                                     16, 0, 0);
  }

  // ---- stage E chunk (tile T, k-eighth KH): 128 rows x 128B ----------------
#define STAGE_E(T, KH)                                                        \
  {                                                                           \
    _Pragma("unroll")                                                         \
    for (int q = 0; q < 2; ++q) {                                             \
      const int rq  = wv * 2 + q;                                             \
      const int row = rq * 8 + (lane >> 3);                                   \
      const int k4l = lane & 7;                                               \
      const int k4g = (k4l ^ rq) & 7;                                         \
      gchar_t* src = (gchar_t*)((const char*)E                                \
          + ((size_t)((T) * BN + row) << 9) + ((KH) << 7) + (k4g << 4));      \
      lchar_t* dst = (lchar_t*)(e_lds + rq * 1024);                           \
      __builtin_amdgcn_global_load_lds(                                       \
          (const __attribute__((address_space(1))) void*)src,                 \
          (__attribute__((address_space(3))) void*)dst, 16, 0, 0);            \
    }                                                                         \
  }

  // ---- xx for my 8 tokens (numpy pairwise 8-acc order), from global --------
  float xx[8], best[8];
  int   bidx[8];
  #pragma unroll
  for (int i = 0; i < 8; ++i) {
    const float4* xr = (const float4*)(Xb + (ty * 8 + i) * DIM);
    float r[8];
    {
      float4 A = xr[0], B = xr[1];
      r[0]=A.x*A.x; r[1]=A.y*A.y; r[2]=A.z*A.z; r[3]=A.w*A.w;
      r[4]=B.x*B.x; r[5]=B.y*B.y; r[6]=B.z*B.z; r[7]=B.w*B.w;
    }
    #pragma unroll
    for (int g = 1; g < 16; ++g) {
      float4 A = xr[2*g], B = xr[2*g+1];
      float s0=A.x*A.x, s1=A.y*A.y, s2=A.z*A.z, s3=A.w*A.w;
      float s4=B.x*B.x, s5=B.y*B.y, s6=B.z*B.z, s7=B.w*B.w;
      r[0]=r[0]+s0; r[1]=r[1]+s1; r[2]=r[2]+s2; r[3]=r[3]+s3;
      r[4]=r[4]+s4; r[5]=r[5]+s5; r[6]=r[6]+s6; r[7]=r[7]+s7;
    }
    xx[i]   = ((r[0]+r[1])+(r[2]+r[3])) + ((r[4]+r[5])+(r[6]+r[7]));
    best[i] = __builtin_inff();
    bidx[i] = 0;
  }

  asm volatile("s_waitcnt vmcnt(0)" ::: "memory");
  __syncthreads();

  const int     tyw = ty & 7;
  const float4* xl  = (const float4*)x_lds;
  float acc[8][8];

  // kk-sweep over one 8-k4 chunk; global k4 = KH*8+kk; sequential-k fmaf
#define KSWEEP(KH)                                                            \
  {                                                                           \
    _Pragma("unroll 2")                                                       \
    for (int kk = 0; kk < 8; ++kk) {                                          \
      float4 xf[8], ef[8];                                                    \
      const int k4p = ((KH) * 8 + kk) ^ tyw;                                  \
      _Pragma("unroll")                                                       \
      for (int i = 0; i < 8; ++i) xf[i] = xl[(ty * 8 + i) * 32 + k4p];        \
      _Pragma("unroll")                                                       \
      for (int j = 0; j < 8; ++j)                                             \
        ef[j] = *(const float4*)(e_lds + (tx * 8 + j) * 128                   \
                                 + (((kk ^ tx) & 7) << 4));                   \
      _Pragma("unroll")                                                       \
      for (int i = 0; i < 8; ++i)                                             \
        _Pragma("unroll")                                                     \
        for (int j = 0; j < 8; ++j) {                                         \
          acc[i][j] = __builtin_fmaf(xf[i].x, ef[j].x, acc[i][j]);            \
          acc[i][j] = __builtin_fmaf(xf[i].y, ef[j].y, acc[i][j]);            \
          acc[i][j] = __builtin_fmaf(xf[i].z, ef[j].z, acc[i][j]);            \
          acc[i][j] = __builtin_fmaf(xf[i].w, ef[j].w, acc[i][j]);            \
        }                                                                     \
    }                                                                         \
  }

  for (int t = 0; t < NT; ++t) {
    #pragma unroll
    for (int i = 0; i < 8; ++i)
      #pragma unroll
      for (int j = 0; j < 8; ++j) acc[i][j] = 0.0f;

    for (int kh = 0; kh < 4; ++kh) {
      __syncthreads();                 // previous chunk consumed by all waves
      STAGE_E(t, kh)
      asm volatile("s_waitcnt vmcnt(0)" ::: "memory");
      __syncthreads();
      KSWEEP(kh)
    }

    // ---- dist = (xx + ee) - 2*dot ; running argmin (strict <, ascending n) --
    const float4* ee4 = (const float4*)(ee + t * BN + tx * 8);
    float4 eeA = ee4[0], eeB = ee4[1];
    float eev[8] = {eeA.x, eeA.y, eeA.z, eeA.w, eeB.x, eeB.y, eeB.z, eeB.w};
    #pragma unroll
    for (int i = 0; i < 8; ++i)
      #pragma unroll
      for (int j = 0; j < 8; ++j) {
        float d = (xx[i] + eev[j]) - 2.0f * acc[i][j];
        int   n = t * BN + tx * 8 + j;
        if (d < best[i]) { best[i] = d; bidx[i] = n; }
      }
  }

  // ---- cross-tx butterfly reduce (lowest index wins on exact tie) ----------
  int rix[8];
  #pragma unroll
  for (int i = 0; i < 8; ++i) {
    float b = best[i]; int ix = bidx[i];
    #pragma unroll
    for (int m = 1; m < 16; m <<= 1) {
      float pb = __shfl_xor(b, m, 64);
      int   pi = __shfl_xor(ix, m, 64);
      if (pb < b || (pb == b && pi < ix)) { b = pb; ix = pi; }
    }
    rix[i] = ix;
  }
  __syncthreads();                      // all KSWEEP reads of x_lds done
  int* idx_s = (int*)x_lds;             // alias: x data dead from here on
  if (tx == 0) {
    #pragma unroll
    for (int i = 0; i < 8; ++i) idx_s[ty * 8 + i] = rix[i];
  }
  __syncthreads();

  // ---- epilogue: out = x + (e - x); idx + histogram ------------------------
  const int   tt = tid >> 1;
  const int   hf = tid & 1;
  const int   fi = idx_s[tt];
  const float* xrow = Xb  + tt * DIM + hf * 64;
  const float* erow = E   + ((size_t)fi << 7) + hf * 64;
  float*       orow = out + ((size_t)blk * BM + tt) * DIM + hf * 64;
  #pragma unroll
  for (int q = 0; q < 16; ++q) {
    float4 xv = *(const float4*)(xrow + q * 4);
    float4 ev = *(const float4*)(erow + q * 4);
    float4 o;
    o.x = xv.x + (ev.x - xv.x);
    o.y = xv.y + (ev.y - xv.y);
    o.z = xv.z + (ev.z - xv.z);
    o.w = xv.w + (ev.w - xv.w);
    *(float4*)(orow + q * 4) = o;
  }
  if (hf == 0) {
    idxg[blk * BM + tt] = fi;
    atomicAdd(cnt_i + fi, 1);
  }
}

// ---------------- prefix + finalize1: cs outputs, cs_ws, CSR offsets ----------
__global__ __launch_bounds__(1024) void prefix_fin1(
    const float* __restrict__ cluster_size, const int* __restrict__ cnt_i,
    float* __restrict__ out_cs, float* __restrict__ cs_ws,
    int* __restrict__ cursor, int* __restrict__ offs) {
  #pragma clang fp contract(off)
  __shared__ float red[1024];
  __shared__ int   sc[1024];
  const int n = threadIdx.x;
  const int cnt = cnt_i[n];
  float ncs = 0.99f * cluster_size[n] + 0.01f * (float)cnt;
  out_cs[n] = ncs;
  red[n] = ncs;
  sc[n]  = cnt;
  __syncthreads();
  for (int s = 512; s > 0; s >>= 1) {
    if (n < s) red[n] = red[n] + red[n + s];
    __syncthreads();
  }
  float ntot = red[0];
  cs_ws[n] = (ncs + 1e-5f) / (ntot + 0.01024f) * ntot;
  for (int d = 1; d < 1024; d <<= 1) {
    int t = (n >= d) ? sc[n - d] : 0;
    __syncthreads();
    sc[n] += t;
    __syncthreads();
  }
  int excl = sc[n] - cnt;
  cursor[n] = excl;
  offs[n]   = excl;
}

// ---------------- scatter tokens into CSR order -------------------------------
__global__ __launch_bounds__(256) void scatter_kernel(
    const int* __restrict__ idxg, int* __restrict__ cursor,
    int* __restrict__ order) {
  const int t  = blockIdx.x * 256 + threadIdx.x;
  const int fi = idxg[t];
  const int slot = atomicAdd(cursor + fi, 1);
  order[slot] = t;
}

// ---------------- per-code sums + finalize2 (fused) ---------------------------
__global__ __launch_bounds__(256) void sums_fin2(
    const float* __restrict__ X, const int* __restrict__ order,
    const int* __restrict__ offs, const int* __restrict__ cnt_i,
    const float* __restrict__ embed_avg, const float* __restrict__ cs_ws,
    float* __restrict__ out_embed, float* __restrict__ out_avg) {
  #pragma clang fp contract(off)
  __shared__ float accs[4][DIM];
  const int c     = blockIdx.x;
  const int lane  = threadIdx.x & 63;
  const int wv    = threadIdx.x >> 6;
  const int start = offs[c];
  const int num   = cnt_i[c];
  float ax0 = 0.0f, ay0 = 0.0f, ax1 = 0.0f, ay1 = 0.0f;
  int u = wv;
  for (; u + 4 < num; u += 8) {
    int t0 = order[start + u];
    int t1 = order[start + u + 4];
    float2 a = *((const float2*)(X + ((size_t)t0 << 7)) + lane);
    float2 b = *((const float2*)(X + ((size_t)t1 << 7)) + lane);
    ax0 = ax0 + a.x; ay0 = ay0 + a.y;
    ax1 = ax1 + b.x; ay1 = ay1 + b.y;
  }
  if (u < num) {
    int t0 = order[start + u];
    float2 a = *((const float2*)(X + ((size_t)t0 << 7)) + lane);
    ax0 = ax0 + a.x; ay0 = ay0 + a.y;
  }
  accs[wv][lane * 2]     = ax0 + ax1;
  accs[wv][lane * 2 + 1] = ay0 + ay1;
  __syncthreads();
  if (wv == 0) {
    float sx = (accs[0][lane*2]   + accs[1][lane*2])
             + (accs[2][lane*2]   + accs[3][lane*2]);
    float sy = (accs[0][lane*2+1] + accs[1][lane*2+1])
             + (accs[2][lane*2+1] + accs[3][lane*2+1]);
    float avx = 0.99f * embed_avg[c * DIM + lane*2]     + 0.01f * sx;
    float avy = 0.99f * embed_avg[c * DIM + lane*2 + 1] + 0.01f * sy;
    float cs  = cs_ws[c];
    out_avg[c * DIM + lane*2]       = avx;
    out_avg[c * DIM + lane*2 + 1]   = avy;
    out_embed[c * DIM + lane*2]     = avx / cs;
    out_embed[c * DIM + lane*2 + 1] = avy / cs;
  }
}

extern "C" void kernel_launch(void* const* d_in, const int* in_sizes, int n_in,
                              void* d_out, int out_size, void* d_ws, size_t ws_size,
                              hipStream_t stream) {
  const float* X  = (const float*)d_in[0];
  const float* E  = (const float*)d_in[1];
  const float* CS = (const float*)d_in[2];
  const float* EA = (const float*)d_in[3];
  float* out = (float*)d_out;
  float* ws  = (float*)d_ws;

  float* eearr  = ws;                       // 1024 f
  float* csarr  = ws + 1024;                // 1024 f
  int*   cnt_i  = (int*)(ws + 2048);        // 1024 i
  int*   cursor = (int*)(ws + 3072);        // 1024 i
  int*   offs   = (int*)(ws + 4096);        // 1024 i
  int*   idxarr = (int*)(ws + 5120);        // 65536 i
  int*   order  = (int*)(ws + 70656);       // 65536 i

  hipMemsetAsync(cnt_i, 0, NCODES * sizeof(int), stream);

  ee_kernel     <<<NCODES / 256, 256, 0, stream>>>(E, eearr);
  vq_main       <<<NTOK / BM,    512, 0, stream>>>(X, E, eearr, out, idxarr, cnt_i);
  prefix_fin1   <<<1, 1024, 0, stream>>>(CS, cnt_i, out + 8519680, csarr,
                                         cursor, offs);
  scatter_kernel<<<NTOK / 256,   256, 0, stream>>>(idxarr, cursor, order);
  sums_fin2     <<<NCODES,       256, 0, stream>>>(X, order, offs, cnt_i, EA,
                                                   csarr, out + 8388608,
                                                   out + 8520704);
}

// Round 8
// 323.452 us; speedup vs baseline: 4.9330x; 1.4073x over previous
//
#include <hip/hip_runtime.h>

#define NTOK   65536
#define NCODES 1024
#define DIM    128
#define BT     256          // tokens per block
#define MARGIN 6.0f
#define CAP    3327

typedef __attribute__((ext_vector_type(8))) short short8;
typedef __attribute__((ext_vector_type(4))) float f32x4;

__device__ __forceinline__ unsigned short f2bf(float f) {
  unsigned u = __float_as_uint(f);
  u += 0x7FFFu + ((u >> 16) & 1u);          // RTNE
  return (unsigned short)(u >> 16);
}

// ---------------- ee[c] = sum(embed[c,:]^2) in numpy pairwise (8-acc) order ----
__global__ __launch_bounds__(256) void ee_kernel(const float* __restrict__ E,
                                                 float* __restrict__ ee) {
  #pragma clang fp contract(off)
  int c = blockIdx.x * blockDim.x + threadIdx.x;
  if (c >= NCODES) return;
  const float4* r4 = (const float4*)(E + (size_t)c * DIM);
  float v[DIM];
  #pragma unroll
  for (int i = 0; i < 32; ++i) {
    float4 q = r4[i];
    v[4*i] = q.x; v[4*i+1] = q.y; v[4*i+2] = q.z; v[4*i+3] = q.w;
  }
  float r[8];
  #pragma unroll
  for (int j = 0; j < 8; ++j) r[j] = v[j] * v[j];
  #pragma unroll
  for (int i = 1; i < 16; ++i) {
    #pragma unroll
    for (int j = 0; j < 8; ++j) { float s = v[8*i+j] * v[8*i+j]; r[j] = r[j] + s; }
  }
  ee[c] = ((r[0]+r[1])+(r[2]+r[3])) + ((r[4]+r[5])+(r[6]+r[7]));
}

// ---------------- E -> bf16 in MFMA B-fragment layout -------------------------
// unit id = (ct*4 + s)*64 + l : lane l of kstep s of code-tile ct holds
// E[ct*16 + (l&15)][32*s + (l>>4)*8 + j], j=0..7  (16 B per unit).
__global__ __launch_bounds__(256) void ebf_kernel(const float* __restrict__ E,
                                                  unsigned short* __restrict__ ebf) {
  const int id = blockIdx.x * 256 + threadIdx.x;    // 0..16383
  const int l  = id & 63;
  const int s  = (id >> 6) & 3;
  const int ct = id >> 8;
  const int c  = ct * 16 + (l & 15);
  const int ko = s * 32 + (l >> 4) * 8;
  const float4* p = (const float4*)(E + (size_t)c * DIM + ko);
  float4 A = p[0], B = p[1];
  short8 v;
  v[0]=f2bf(A.x); v[1]=f2bf(A.y); v[2]=f2bf(A.z); v[3]=f2bf(A.w);
  v[4]=f2bf(B.x); v[5]=f2bf(B.y); v[6]=f2bf(B.z); v[7]=f2bf(B.w);
  ((short8*)ebf)[id] = v;
}

// ---------------- main: MFMA approx sweep + margin prune + exact rescore ------
// 512 threads = 8 waves; wave w owns codes [w*128, w*128+128) as B-frags in
// REGISTERS (loaded once). X (256 tokens) converted to bf16 in swizzled LDS.
// Phase A: MFMA sweep -> per-token approx min (cross-lane+cross-wave merge).
// Phase B: MFMA sweep again -> candidates with d < min+MARGIN into LDS list.
// Phase C: exact f32 sequential-fmaf rescore of candidates, u64 atomicMin
// (sortable d | code) -> exact argmin w/ lowest-index ties. xx omitted: it is
// a per-token constant and cancels in argmin.
__global__ __launch_bounds__(512, 2) void vq_main(
    const float* __restrict__ X, const float* __restrict__ E,
    const unsigned short* __restrict__ ebf, const float* __restrict__ ee,
    float* __restrict__ out, int* __restrict__ idxg, int* __restrict__ cnt_i) {
  #pragma clang fp contract(off)
  __shared__ __align__(16) char x_lds[BT * 256];    // 64 KB bf16 X
  __shared__ __align__(16) char region[16384];      // phaseA best / overlay

  const int tid  = threadIdx.x;
  const int lane = tid & 63;
  const int wv   = tid >> 6;
  const long blk = blockIdx.x;
  const float* Xb = X + (size_t)blk * BT * DIM;

  float* bestA = (float*)region;                       // [8][256]
  int*   idxA  = (int*)(region + 8192);                // [8][256]
  float* thrf  = (float*)region;                       // overlay [256]
  unsigned long long* best64 = (unsigned long long*)(region + 1024);  // [256]
  int*      cand_n = (int*)(region + 3072);
  unsigned* cand   = (unsigned*)(region + 3076);       // CAP entries

  // ---- B fragments: wave's 128 codes (8 tiles x 4 ksteps), 128 VGPRs -------
  short8 bfr[8][4];
  const short8* ebv = (const short8*)ebf;
  #pragma unroll
  for (int ct = 0; ct < 8; ++ct)
    #pragma unroll
    for (int s = 0; s < 4; ++s)
      bfr[ct][s] = ebv[((wv * 8 + ct) * 4 + s) * 64 + lane];

  const int cb = wv * 128;
  float eev[8];
  #pragma unroll
  for (int ct = 0; ct < 8; ++ct) eev[ct] = ee[cb + ct * 16 + (lane & 15)];

  // ---- stage X -> bf16 LDS; octet o of row r at slot o^(r&7) (low3 XOR) ----
  {
    const int r = tid >> 1, h = tid & 1;
    const float4* p4 = (const float4*)(Xb + r * DIM + h * 64);
    #pragma unroll
    for (int q = 0; q < 8; ++q) {
      float4 A = p4[2 * q], B = p4[2 * q + 1];
      short8 v;
      v[0]=f2bf(A.x); v[1]=f2bf(A.y); v[2]=f2bf(A.z); v[3]=f2bf(A.w);
      v[4]=f2bf(B.x); v[5]=f2bf(B.y); v[6]=f2bf(B.z); v[7]=f2bf(B.w);
      const int oct = h * 8 + q;
      *(short8*)(x_lds + r * 256 + ((oct ^ (r & 7)) << 4)) = v;
    }
  }
  __syncthreads();

  // A-frag: row tt*16+(lane&15), k-octet 4s+(lane>>4), same XOR swizzle
#define AFRAG(TT, S) (*(const short8*)(x_lds + ((TT) * 16 + (lane & 15)) * 256 \
                       + ((((S) * 4 + (lane >> 4)) ^ (lane & 7)) << 4)))

  // =========================== phase A: approx min ==========================
  for (int tt = 0; tt < 16; ++tt) {
    short8 a0 = AFRAG(tt, 0), a1 = AFRAG(tt, 1), a2 = AFRAG(tt, 2), a3 = AFRAG(tt, 3);
    float bv[4] = {__builtin_inff(), __builtin_inff(), __builtin_inff(), __builtin_inff()};
    int   bix[4] = {0, 0, 0, 0};
    #pragma unroll
    for (int ct = 0; ct < 8; ++ct) {
      f32x4 acc = {0.f, 0.f, 0.f, 0.f};
      acc = __builtin_amdgcn_mfma_f32_16x16x32_bf16(a0, bfr[ct][0], acc, 0, 0, 0);
      acc = __builtin_amdgcn_mfma_f32_16x16x32_bf16(a1, bfr[ct][1], acc, 0, 0, 0);
      acc = __builtin_amdgcn_mfma_f32_16x16x32_bf16(a2, bfr[ct][2], acc, 0, 0, 0);
      acc = __builtin_amdgcn_mfma_f32_16x16x32_bf16(a3, bfr[ct][3], acc, 0, 0, 0);
      const int code = cb + ct * 16 + (lane & 15);
      #pragma unroll
      for (int rg = 0; rg < 4; ++rg) {
        float d = eev[ct] - 2.0f * acc[rg];
        if (d < bv[rg]) { bv[rg] = d; bix[rg] = code; }
      }
    }
    #pragma unroll
    for (int rg = 0; rg < 4; ++rg) {
      float b = bv[rg]; int ix = bix[rg];
      #pragma unroll
      for (int m = 1; m < 16; m <<= 1) {
        float pb = __shfl_xor(b, m, 64);
        int   pi = __shfl_xor(ix, m, 64);
        if (pb < b || (pb == b && pi < ix)) { b = pb; ix = pi; }
      }
      if ((lane & 15) == 0) {
        const int t = tt * 16 + (lane >> 4) * 4 + rg;
        bestA[wv * 256 + t] = b;
        idxA [wv * 256 + t] = ix;
      }
    }
  }
  __syncthreads();

  // ---- cross-wave merge -> thresholds (reads, barrier, then overlay writes) -
  float fb = 0.0f; int fi = 0;
  if (tid < 256) {
    fb = bestA[tid]; fi = idxA[tid];
    #pragma unroll
    for (int w = 1; w < 8; ++w) {
      float b2 = bestA[w * 256 + tid]; int i2 = idxA[w * 256 + tid];
      if (b2 < fb || (b2 == fb && i2 < fi)) { fb = b2; fi = i2; }
    }
  }
  __syncthreads();
  if (tid < 256) { thrf[tid] = fb + MARGIN; best64[tid] = ~0ull; }
  if (tid == 0) *cand_n = 0;
  __syncthreads();

  // =========================== phase B: gather candidates ===================
  for (int tt = 0; tt < 16; ++tt) {
    float thv[4];
    #pragma unroll
    for (int rg = 0; rg < 4; ++rg) thv[rg] = thrf[tt * 16 + (lane >> 4) * 4 + rg];
    short8 a0 = AFRAG(tt, 0), a1 = AFRAG(tt, 1), a2 = AFRAG(tt, 2), a3 = AFRAG(tt, 3);
    #pragma unroll
    for (int ct = 0; ct < 8; ++ct) {
      f32x4 acc = {0.f, 0.f, 0.f, 0.f};
      acc = __builtin_amdgcn_mfma_f32_16x16x32_bf16(a0, bfr[ct][0], acc, 0, 0, 0);
      acc = __builtin_amdgcn_mfma_f32_16x16x32_bf16(a1, bfr[ct][1], acc, 0, 0, 0);
      acc = __builtin_amdgcn_mfma_f32_16x16x32_bf16(a2, bfr[ct][2], acc, 0, 0, 0);
      acc = __builtin_amdgcn_mfma_f32_16x16x32_bf16(a3, bfr[ct][3], acc, 0, 0, 0);
      const int code = cb + ct * 16 + (lane & 15);
      #pragma unroll
      for (int rg = 0; rg < 4; ++rg) {
        float d = eev[ct] - 2.0f * acc[rg];
        if (d < thv[rg]) {
          int slot = atomicAdd(cand_n, 1);
          if (slot < CAP)
            cand[slot] = ((unsigned)(tt * 16 + (lane >> 4) * 4 + rg) << 10)
                       | (unsigned)code;
        }
      }
    }
  }
  __syncthreads();

  // =========================== phase C: exact rescore =======================
  {
    int cn = *cand_n;
    const int nc = cn < CAP ? cn : CAP;
    for (int i = tid; i < nc; i += 512) {
      const unsigned pc = cand[i];
      const int t = pc >> 10, c = pc & 1023;
      const float* xr = Xb + t * DIM;
      const float* er = E + (size_t)c * DIM;
      float dot = 0.0f;
      #pragma unroll
      for (int k = 0; k < DIM; ++k) dot = __builtin_fmaf(xr[k], er[k], dot);
      float d = ee[c] - 2.0f * dot;
      unsigned u = __float_as_uint(d);
      u ^= (unsigned)((int)u >> 31) | 0x80000000u;     // sortable float key
      unsigned long long key = ((unsigned long long)u << 32) | (unsigned)c;
      atomicMin(best64 + t, key);
    }
  }
  __syncthreads();

  // ---- epilogue: idx + histogram + out = x + (e - x) -----------------------
  if (tid < 256) {
    const int c0 = (int)(best64[tid] & 1023ull);
    idxg[blk * BT + tid] = c0;
    atomicAdd(cnt_i + c0, 1);
  }
  const int tt2 = tid >> 1, hf = tid & 1;
  const int fi2 = (int)(best64[tt2] & 1023ull);
  const float* xrow = Xb  + tt2 * DIM + hf * 64;
  const float* erow = E   + ((size_t)fi2 << 7) + hf * 64;
  float*       orow = out + ((size_t)blk * BT + tt2) * DIM + hf * 64;
  #pragma unroll
  for (int q = 0; q < 16; ++q) {
    float4 xv = *(const float4*)(xrow + q * 4);
    float4 ev = *(const float4*)(erow + q * 4);
    float4 o;
    o.x = xv.x + (ev.x - xv.x);
    o.y = xv.y + (ev.y - xv.y);
    o.z = xv.z + (ev.z - xv.z);
    o.w = xv.w + (ev.w - xv.w);
    *(float4*)(orow + q * 4) = o;
  }
}

// ---------------- prefix + finalize1: cs outputs, cs_ws, CSR offsets ----------
__global__ __launch_bounds__(1024) void prefix_fin1(
    const float* __restrict__ cluster_size, const int* __restrict__ cnt_i,
    float* __restrict__ out_cs, float* __restrict__ cs_ws,
    int* __restrict__ cursor, int* __restrict__ offs) {
  #pragma clang fp contract(off)
  __shared__ float red[1024];
  __shared__ int   sc[1024];
  const int n = threadIdx.x;
  const int cnt = cnt_i[n];
  float ncs = 0.99f * cluster_size[n] + 0.01f * (float)cnt;
  out_cs[n] = ncs;
  red[n] = ncs;
  sc[n]  = cnt;
  __syncthreads();
  for (int s = 512; s > 0; s >>= 1) {
    if (n < s) red[n] = red[n] + red[n + s];
    __syncthreads();
  }
  float ntot = red[0];
  cs_ws[n] = (ncs + 1e-5f) / (ntot + 0.01024f) * ntot;
  for (int d = 1; d < 1024; d <<= 1) {
    int t = (n >= d) ? sc[n - d] : 0;
    __syncthreads();
    sc[n] += t;
    __syncthreads();
  }
  int excl = sc[n] - cnt;
  cursor[n] = excl;
  offs[n]   = excl;
}

// ---------------- scatter tokens into CSR order -------------------------------
__global__ __launch_bounds__(256) void scatter_kernel(
    const int* __restrict__ idxg, int* __restrict__ cursor,
    int* __restrict__ order) {
  const int t  = blockIdx.x * 256 + threadIdx.x;
  const int fi = idxg[t];
  const int slot = atomicAdd(cursor + fi, 1);
  order[slot] = t;
}

// ---------------- per-code sums + finalize2 (fused) ---------------------------
__global__ __launch_bounds__(256) void sums_fin2(
    const float* __restrict__ X, const int* __restrict__ order,
    const int* __restrict__ offs, const int* __restrict__ cnt_i,
    const float* __restrict__ embed_avg, const float* __restrict__ cs_ws,
    float* __restrict__ out_embed, float* __restrict__ out_avg) {
  #pragma clang fp contract(off)
  __shared__ float accs[4][DIM];
  const int c     = blockIdx.x;
  const int lane  = threadIdx.x & 63;
  const int wv    = threadIdx.x >> 6;
  const int start = offs[c];
  const int num   = cnt_i[c];
  float ax0 = 0.0f, ay0 = 0.0f, ax1 = 0.0f, ay1 = 0.0f;
  int u = wv;
  for (; u + 4 < num; u += 8) {
    int t0 = order[start + u];
    int t1 = order[start + u + 4];
    float2 a = *((const float2*)(X + ((size_t)t0 << 7)) + lane);
    float2 b = *((const float2*)(X + ((size_t)t1 << 7)) + lane);
    ax0 = ax0 + a.x; ay0 = ay0 + a.y;
    ax1 = ax1 + b.x; ay1 = ay1 + b.y;
  }
  if (u < num) {
    int t0 = order[start + u];
    float2 a = *((const float2*)(X + ((size_t)t0 << 7)) + lane);
    ax0 = ax0 + a.x; ay0 = ay0 + a.y;
  }
  accs[wv][lane * 2]     = ax0 + ax1;
  accs[wv][lane * 2 + 1] = ay0 + ay1;
  __syncthreads();
  if (wv == 0) {
    float sx = (accs[0][lane*2]   + accs[1][lane*2])
             + (accs[2][lane*2]   + accs[3][lane*2]);
    float sy = (accs[0][lane*2+1] + accs[1][lane*2+1])
             + (accs[2][lane*2+1] + accs[3][lane*2+1]);
    float avx = 0.99f * embed_avg[c * DIM + lane*2]     + 0.01f * sx;
    float avy = 0.99f * embed_avg[c * DIM + lane*2 + 1] + 0.01f * sy;
    float cs  = cs_ws[c];
    out_avg[c * DIM + lane*2]       = avx;
    out_avg[c * DIM + lane*2 + 1]   = avy;
    out_embed[c * DIM + lane*2]     = avx / cs;
    out_embed[c * DIM + lane*2 + 1] = avy / cs;
  }
}

extern "C" void kernel_launch(void* const* d_in, const int* in_sizes, int n_in,
                              void* d_out, int out_size, void* d_ws, size_t ws_size,
                              hipStream_t stream) {
  const float* X  = (const float*)d_in[0];
  const float* E  = (const float*)d_in[1];
  const float* CS = (const float*)d_in[2];
  const float* EA = (const float*)d_in[3];
  float* out = (float*)d_out;
  float* ws  = (float*)d_ws;

  float* eearr  = ws;                        // 1024 f
  float* csarr  = ws + 1024;                 // 1024 f
  int*   cnt_i  = (int*)(ws + 2048);         // 1024 i
  int*   cursor = (int*)(ws + 3072);         // 1024 i
  int*   offs   = (int*)(ws + 4096);         // 1024 i
  int*   idxarr = (int*)(ws + 5120);         // 65536 i
  int*   order  = (int*)(ws + 70656);        // 65536 i
  unsigned short* ebf = (unsigned short*)(ws + 136192);  // 256 KB bf16 frags

  hipMemsetAsync(cnt_i, 0, NCODES * sizeof(int), stream);

  ee_kernel     <<<NCODES / 256, 256, 0, stream>>>(E, eearr);
  ebf_kernel    <<<64,           256, 0, stream>>>(E, ebf);
  vq_main       <<<NTOK / BT,    512, 0, stream>>>(X, E, ebf, eearr, out,
                                                   idxarr, cnt_i);
  prefix_fin1   <<<1, 1024, 0, stream>>>(CS, cnt_i, out + 8519680, csarr,
                                         cursor, offs);
  scatter_kernel<<<NTOK / 256,   256, 0, stream>>>(idxarr, cursor, order);
  sums_fin2     <<<NCODES,       256, 0, stream>>>(X, order, offs, cnt_i, EA,
                                                   csarr, out + 8388608,
                                                   out + 8520704);
}

// Round 9
// 186.387 us; speedup vs baseline: 8.5607x; 1.7354x over previous
//
#include <hip/hip_runtime.h>

#define NTOK   65536
#define NCODES 1024
#define DIM    128
#define BT     256          // tokens per block
#define MARGIN 6.0f
#define CAP    3326

typedef __attribute__((ext_vector_type(8))) short short8;
typedef __attribute__((ext_vector_type(4))) float f32x4;
typedef const __attribute__((address_space(1))) char gchar_t;
typedef __attribute__((address_space(3))) char lchar_t;

__device__ __forceinline__ unsigned short f2bf(float f) {
  unsigned u = __float_as_uint(f);
  u += 0x7FFFu + ((u >> 16) & 1u);          // RTNE
  return (unsigned short)(u >> 16);
}

// ---------------- ee[c] = sum(embed[c,:]^2) in numpy pairwise (8-acc) order ----
__global__ __launch_bounds__(256) void ee_kernel(const float* __restrict__ E,
                                                 float* __restrict__ ee) {
  #pragma clang fp contract(off)
  int c = blockIdx.x * blockDim.x + threadIdx.x;
  if (c >= NCODES) return;
  const float4* r4 = (const float4*)(E + (size_t)c * DIM);
  float v[DIM];
  #pragma unroll
  for (int i = 0; i < 32; ++i) {
    float4 q = r4[i];
    v[4*i] = q.x; v[4*i+1] = q.y; v[4*i+2] = q.z; v[4*i+3] = q.w;
  }
  float r[8];
  #pragma unroll
  for (int j = 0; j < 8; ++j) r[j] = v[j] * v[j];
  #pragma unroll
  for (int i = 1; i < 16; ++i) {
    #pragma unroll
    for (int j = 0; j < 8; ++j) { float s = v[8*i+j] * v[8*i+j]; r[j] = r[j] + s; }
  }
  ee[c] = ((r[0]+r[1])+(r[2]+r[3])) + ((r[4]+r[5])+(r[6]+r[7]));
}

// ---------------- E -> bf16 in MFMA B-fragment layout (verified r8) -----------
// unit id = (ct*4 + s)*64 + l : lane l holds E[ct*16+(l&15)][s*32+(l>>4)*8+j].
__global__ __launch_bounds__(256) void ebf_kernel(const float* __restrict__ E,
                                                  unsigned short* __restrict__ ebf) {
  const int id = blockIdx.x * 256 + threadIdx.x;    // 0..16383
  const int l  = id & 63;
  const int s  = (id >> 6) & 3;
  const int ct = id >> 8;
  const int c  = ct * 16 + (l & 15);
  const int ko = s * 32 + (l >> 4) * 8;
  const float4* p = (const float4*)(E + (size_t)c * DIM + ko);
  float4 A = p[0], B = p[1];
  short8 v;
  v[0]=f2bf(A.x); v[1]=f2bf(A.y); v[2]=f2bf(A.z); v[3]=f2bf(A.w);
  v[4]=f2bf(B.x); v[5]=f2bf(B.y); v[6]=f2bf(B.z); v[7]=f2bf(B.w);
  ((short8*)ebf)[id] = v;
}

// ---------------- main: shared-E LDS GEMM, A-frags in regs --------------------
// 512 threads = 8 waves; wave wv owns token-tiles tt=2wv,2wv+1 (A-frags in 32
// VGPRs, converted straight from global X). E-frags staged per 128-code tile
// (32KB frag-linear, double-buffered) -> lane-contiguous conflict-free
// ds_read_b128. Phase A: approx min per token (no cross-wave merge needed).
// Phase B: re-sweep, gather candidates d < min+MARGIN. Phase C: exact f32
// rescore, u64 atomicMin (sortable d | code) -> lowest-index-tie argmin.
__global__ __launch_bounds__(512, 1) void vq_main(
    const float* __restrict__ X, const float* __restrict__ E,
    const unsigned short* __restrict__ ebf, const float* __restrict__ ee,
    float* __restrict__ out, int* __restrict__ idxg, int* __restrict__ cnt_i) {
  #pragma clang fp contract(off)
  __shared__ __align__(16) char e_lds[2 * 32768];
  __shared__ __align__(16) char region[16384];

  const int tid  = threadIdx.x;
  const int lane = tid & 63;
  const int wv   = tid >> 6;
  const long blk = blockIdx.x;
  const float* Xb = X + (size_t)blk * BT * DIM;

  float* thrf = (float*)region;                                    // 256 f
  unsigned long long* best64 = (unsigned long long*)(region + 1024); // 256 u64
  int*      cand_n = (int*)(region + 3072);
  unsigned* cand   = (unsigned*)(region + 3076);                   // CAP

  // stage E tile CT (32 frag-units = 32KB) into buffer BUF
#define STAGE_E(CT, BUF)                                                      \
  {                                                                           \
    _Pragma("unroll")                                                         \
    for (int q = 0; q < 4; ++q) {                                             \
      const int u = wv * 4 + q;                                               \
      gchar_t* src = (gchar_t*)((const char*)ebf                              \
                      + ((size_t)(((CT) * 32 + u) * 64 + lane) << 4));        \
      lchar_t* dst = (lchar_t*)(e_lds + (BUF) * 32768 + u * 1024);            \
      __builtin_amdgcn_global_load_lds(                                       \
          (const __attribute__((address_space(1))) void*)src,                 \
          (__attribute__((address_space(3))) void*)dst, 16, 0, 0);            \
    }                                                                         \
  }

  STAGE_E(0, 0)

  // ---- A-frags: convert my 2 token-tiles straight to registers -------------
  short8 afr[2][4];
  #pragma unroll
  for (int t2 = 0; t2 < 2; ++t2) {
    const int row = (wv * 2 + t2) * 16 + (lane & 15);
    #pragma unroll
    for (int s = 0; s < 4; ++s) {
      const float4* p = (const float4*)(Xb + row * DIM + (s * 4 + (lane >> 4)) * 8);
      float4 A = p[0], B = p[1];
      short8 v;
      v[0]=f2bf(A.x); v[1]=f2bf(A.y); v[2]=f2bf(A.z); v[3]=f2bf(A.w);
      v[4]=f2bf(B.x); v[5]=f2bf(B.y); v[6]=f2bf(B.z); v[7]=f2bf(B.w);
      afr[t2][s] = v;
    }
  }

  float bv[2][4];
  #pragma unroll
  for (int t2 = 0; t2 < 2; ++t2)
    #pragma unroll
    for (int rg = 0; rg < 4; ++rg) bv[t2][rg] = __builtin_inff();

  asm volatile("s_waitcnt vmcnt(0)" ::: "memory");
  __syncthreads();

  // =========================== phase A: approx min ==========================
  for (int ctile = 0; ctile < 8; ++ctile) {
    if (ctile < 7) STAGE_E(ctile + 1, (ctile + 1) & 1)
    const char* eb = e_lds + (ctile & 1) * 32768;
    #pragma unroll 2
    for (int ct = 0; ct < 8; ++ct) {
      short8 b0 = *(const short8*)(eb + (ct * 4 + 0) * 1024 + lane * 16);
      short8 b1 = *(const short8*)(eb + (ct * 4 + 1) * 1024 + lane * 16);
      short8 b2 = *(const short8*)(eb + (ct * 4 + 2) * 1024 + lane * 16);
      short8 b3 = *(const short8*)(eb + (ct * 4 + 3) * 1024 + lane * 16);
      float eevv = ee[ctile * 128 + ct * 16 + (lane & 15)];
      #pragma unroll
      for (int t2 = 0; t2 < 2; ++t2) {
        f32x4 acc = {0.f, 0.f, 0.f, 0.f};
        acc = __builtin_amdgcn_mfma_f32_16x16x32_bf16(afr[t2][0], b0, acc, 0, 0, 0);
        acc = __builtin_amdgcn_mfma_f32_16x16x32_bf16(afr[t2][1], b1, acc, 0, 0, 0);
        acc = __builtin_amdgcn_mfma_f32_16x16x32_bf16(afr[t2][2], b2, acc, 0, 0, 0);
        acc = __builtin_amdgcn_mfma_f32_16x16x32_bf16(afr[t2][3], b3, acc, 0, 0, 0);
        #pragma unroll
        for (int rg = 0; rg < 4; ++rg) {
          float d = eevv - 2.0f * acc[rg];
          if (d < bv[t2][rg]) bv[t2][rg] = d;
        }
      }
    }
    asm volatile("s_waitcnt vmcnt(0)" ::: "memory");
    __syncthreads();
  }

  // ---- per-token threshold = min + MARGIN (16-lane shuffle min) ------------
  #pragma unroll
  for (int t2 = 0; t2 < 2; ++t2)
    #pragma unroll
    for (int rg = 0; rg < 4; ++rg) {
      float b = bv[t2][rg];
      #pragma unroll
      for (int m = 1; m < 16; m <<= 1) {
        float pb = __shfl_xor(b, m, 64);
        if (pb < b) b = pb;
      }
      if ((lane & 15) == 0)
        thrf[(wv * 2 + t2) * 16 + (lane >> 4) * 4 + rg] = b + MARGIN;
    }
  __syncthreads();
  if (tid < 256) best64[tid] = ~0ull;
  if (tid == 0) *cand_n = 0;
  __syncthreads();

  float thv[2][4];
  #pragma unroll
  for (int t2 = 0; t2 < 2; ++t2)
    #pragma unroll
    for (int rg = 0; rg < 4; ++rg)
      thv[t2][rg] = thrf[(wv * 2 + t2) * 16 + (lane >> 4) * 4 + rg];

  // =========================== phase B: gather candidates ===================
  STAGE_E(0, 0)
  asm volatile("s_waitcnt vmcnt(0)" ::: "memory");
  __syncthreads();
  for (int ctile = 0; ctile < 8; ++ctile) {
    if (ctile < 7) STAGE_E(ctile + 1, (ctile + 1) & 1)
    const char* eb = e_lds + (ctile & 1) * 32768;
    #pragma unroll 2
    for (int ct = 0; ct < 8; ++ct) {
      short8 b0 = *(const short8*)(eb + (ct * 4 + 0) * 1024 + lane * 16);
      short8 b1 = *(const short8*)(eb + (ct * 4 + 1) * 1024 + lane * 16);
      short8 b2 = *(const short8*)(eb + (ct * 4 + 2) * 1024 + lane * 16);
      short8 b3 = *(const short8*)(eb + (ct * 4 + 3) * 1024 + lane * 16);
      float eevv = ee[ctile * 128 + ct * 16 + (lane & 15)];
      const int code = ctile * 128 + ct * 16 + (lane & 15);
      #pragma unroll
      for (int t2 = 0; t2 < 2; ++t2) {
        f32x4 acc = {0.f, 0.f, 0.f, 0.f};
        acc = __builtin_amdgcn_mfma_f32_16x16x32_bf16(afr[t2][0], b0, acc, 0, 0, 0);
        acc = __builtin_amdgcn_mfma_f32_16x16x32_bf16(afr[t2][1], b1, acc, 0, 0, 0);
        acc = __builtin_amdgcn_mfma_f32_16x16x32_bf16(afr[t2][2], b2, acc, 0, 0, 0);
        acc = __builtin_amdgcn_mfma_f32_16x16x32_bf16(afr[t2][3], b3, acc, 0, 0, 0);
        #pragma unroll
        for (int rg = 0; rg < 4; ++rg) {
          float d = eevv - 2.0f * acc[rg];
          if (d < thv[t2][rg]) {
            int slot = atomicAdd(cand_n, 1);
            if (slot < CAP) {
              const int token = (wv * 2 + t2) * 16 + (lane >> 4) * 4 + rg;
              cand[slot] = ((unsigned)token << 10) | (unsigned)code;
            }
          }
        }
      }
    }
    asm volatile("s_waitcnt vmcnt(0)" ::: "memory");
    __syncthreads();
  }
  __syncthreads();

  // =========================== phase C: exact rescore =======================
  {
    int cn = *cand_n;
    const int nc = cn < CAP ? cn : CAP;
    for (int i = tid; i < nc; i += 512) {
      const unsigned pc = cand[i];
      const int t = pc >> 10, c = pc & 1023;
      const float* xr = Xb + t * DIM;
      const float* er = E + (size_t)c * DIM;
      float dot = 0.0f;
      #pragma unroll
      for (int k = 0; k < DIM; ++k) dot = __builtin_fmaf(xr[k], er[k], dot);
      float d = ee[c] - 2.0f * dot;
      unsigned u = __float_as_uint(d);
      u ^= (unsigned)((int)u >> 31) | 0x80000000u;     // sortable float key
      unsigned long long key = ((unsigned long long)u << 32) | (unsigned)c;
      atomicMin(best64 + t, key);
    }
  }
  __syncthreads();

  // ---- epilogue: idx + histogram + out = x + (e - x) -----------------------
  if (tid < 256) {
    const int c0 = (int)(best64[tid] & 1023ull);
    idxg[blk * BT + tid] = c0;
    atomicAdd(cnt_i + c0, 1);
  }
  const int tt2 = tid >> 1, hf = tid & 1;
  const int fi2 = (int)(best64[tt2] & 1023ull);
  const float* xrow = Xb  + tt2 * DIM + hf * 64;
  const float* erow = E   + ((size_t)fi2 << 7) + hf * 64;
  float*       orow = out + ((size_t)blk * BT + tt2) * DIM + hf * 64;
  #pragma unroll
  for (int q = 0; q < 16; ++q) {
    float4 xv = *(const float4*)(xrow + q * 4);
    float4 ev = *(const float4*)(erow + q * 4);
    float4 o;
    o.x = xv.x + (ev.x - xv.x);
    o.y = xv.y + (ev.y - xv.y);
    o.z = xv.z + (ev.z - xv.z);
    o.w = xv.w + (ev.w - xv.w);
    *(float4*)(orow + q * 4) = o;
  }
}

// ---------------- prefix + finalize1: cs outputs, cs_ws, CSR offsets ----------
__global__ __launch_bounds__(1024) void prefix_fin1(
    const float* __restrict__ cluster_size, const int* __restrict__ cnt_i,
    float* __restrict__ out_cs, float* __restrict__ cs_ws,
    int* __restrict__ cursor, int* __restrict__ offs) {
  #pragma clang fp contract(off)
  __shared__ float red[1024];
  __shared__ int   sc[1024];
  const int n = threadIdx.x;
  const int cnt = cnt_i[n];
  float ncs = 0.99f * cluster_size[n] + 0.01f * (float)cnt;
  out_cs[n] = ncs;
  red[n] = ncs;
  sc[n]  = cnt;
  __syncthreads();
  for (int s = 512; s > 0; s >>= 1) {
    if (n < s) red[n] = red[n] + red[n + s];
    __syncthreads();
  }
  float ntot = red[0];
  cs_ws[n] = (ncs + 1e-5f) / (ntot + 0.01024f) * ntot;
  for (int d = 1; d < 1024; d <<= 1) {
    int t = (n >= d) ? sc[n - d] : 0;
    __syncthreads();
    sc[n] += t;
    __syncthreads();
  }
  int excl = sc[n] - cnt;
  cursor[n] = excl;
  offs[n]   = excl;
}

// ---------------- scatter tokens into CSR order -------------------------------
__global__ __launch_bounds__(256) void scatter_kernel(
    const int* __restrict__ idxg, int* __restrict__ cursor,
    int* __restrict__ order) {
  const int t  = blockIdx.x * 256 + threadIdx.x;
  const int fi = idxg[t];
  const int slot = atomicAdd(cursor + fi, 1);
  order[slot] = t;
}

// ---------------- sums: fixed 64-entry CSR chunks per wave, MLP-friendly ------
// Wave walks 64 consecutive CSR entries with 8-deep prefetched row loads;
// flushes per-cluster partials via f32 atomics (~2K segments total, ~1MB).
__global__ __launch_bounds__(256) void sums_chunk(
    const float* __restrict__ X, const int* __restrict__ order,
    const int* __restrict__ idxg, float* __restrict__ sums) {
  #pragma clang fp contract(off)
  const int lane = threadIdx.x & 63;
  const int base = blockIdx.x * 256 + (threadIdx.x >> 6) * 64;
  const int tl = order[base + lane];
  const int cl = idxg[tl];
  float ax = 0.f, ay = 0.f;
  int cprev = __shfl(cl, 0, 64);
  #pragma unroll
  for (int j0 = 0; j0 < 64; j0 += 8) {
    int tj[8], cj[8];
    float2 buf[8];
    #pragma unroll
    for (int q = 0; q < 8; ++q) tj[q] = __shfl(tl, j0 + q, 64);
    #pragma unroll
    for (int q = 0; q < 8; ++q)
      buf[q] = *((const float2*)(X + ((size_t)tj[q] << 7)) + lane);
    #pragma unroll
    for (int q = 0; q < 8; ++q) cj[q] = __shfl(cl, j0 + q, 64);
    #pragma unroll
    for (int q = 0; q < 8; ++q) {
      if (cj[q] != cprev) {                       // wave-uniform branch
        atomicAdd(sums + cprev * DIM + lane * 2,     ax);
        atomicAdd(sums + cprev * DIM + lane * 2 + 1, ay);
        ax = 0.f; ay = 0.f; cprev = cj[q];
      }
      ax = ax + buf[q].x;
      ay = ay + buf[q].y;
    }
  }
  atomicAdd(sums + cprev * DIM + lane * 2,     ax);
  atomicAdd(sums + cprev * DIM + lane * 2 + 1, ay);
}

// ---------------- finalize2: EMA + divide -------------------------------------
__global__ __launch_bounds__(256) void finalize2(
    const float* __restrict__ embed_avg, const float* __restrict__ sums,
    const float* __restrict__ cs_ws, float* __restrict__ out_embed,
    float* __restrict__ out_avg) {
  #pragma clang fp contract(off)
  int i = blockIdx.x * 256 + threadIdx.x;
  float av = 0.99f * embed_avg[i] + 0.01f * sums[i];
  out_avg[i]   = av;
  out_embed[i] = av / cs_ws[i >> 7];
}

extern "C" void kernel_launch(void* const* d_in, const int* in_sizes, int n_in,
                              void* d_out, int out_size, void* d_ws, size_t ws_size,
                              hipStream_t stream) {
  const float* X  = (const float*)d_in[0];
  const float* E  = (const float*)d_in[1];
  const float* CS = (const float*)d_in[2];
  const float* EA = (const float*)d_in[3];
  float* out = (float*)d_out;
  float* ws  = (float*)d_ws;

  int*   cnt_i  = (int*)ws;                  // 1024 i   } zeroed together
  float* sums   = ws + 1024;                 // 131072 f }
  float* eearr  = ws + 132096;               // 1024 f
  float* csarr  = ws + 133120;               // 1024 f
  int*   cursor = (int*)(ws + 134144);       // 1024 i
  int*   offs   = (int*)(ws + 135168);       // 1024 i
  int*   idxarr = (int*)(ws + 136192);       // 65536 i
  int*   order  = (int*)(ws + 201728);       // 65536 i
  unsigned short* ebf = (unsigned short*)(ws + 267264);  // 256 KB bf16 frags

  hipMemsetAsync(d_ws, 0, 132096 * sizeof(float), stream);

  ee_kernel     <<<NCODES / 256, 256, 0, stream>>>(E, eearr);
  ebf_kernel    <<<64,           256, 0, stream>>>(E, ebf);
  vq_main       <<<NTOK / BT,    512, 0, stream>>>(X, E, ebf, eearr, out,
                                                   idxarr, cnt_i);
  prefix_fin1   <<<1, 1024, 0, stream>>>(CS, cnt_i, out + 8519680, csarr,
                                         cursor, offs);
  scatter_kernel<<<NTOK / 256,   256, 0, stream>>>(idxarr, cursor, order);
  sums_chunk    <<<NTOK / 256,   256, 0, stream>>>(X, order, idxarr, sums);
  finalize2     <<<131072 / 256, 256, 0, stream>>>(EA, sums, csarr,
                                                   out + 8388608, out + 8520704);
}

// Round 10
// 172.997 us; speedup vs baseline: 9.2233x; 1.0774x over previous
//
#include <hip/hip_runtime.h>

#define NTOK   65536
#define NCODES 1024
#define DIM    128
#define BT     128          // tokens per block
#define MARGIN 6.0f
#define CAP    2047

typedef __attribute__((ext_vector_type(8))) short short8;
typedef __attribute__((ext_vector_type(4))) float f32x4;
typedef const __attribute__((address_space(1))) char gchar_t;
typedef __attribute__((address_space(3))) char lchar_t;

__device__ __forceinline__ unsigned short f2bf(float f) {
  unsigned u = __float_as_uint(f);
  u += 0x7FFFu + ((u >> 16) & 1u);          // RTNE
  return (unsigned short)(u >> 16);
}

// ---------------- ee[c] = sum(embed[c,:]^2) in numpy pairwise (8-acc) order ----
__global__ __launch_bounds__(256) void ee_kernel(const float* __restrict__ E,
                                                 float* __restrict__ ee) {
  #pragma clang fp contract(off)
  int c = blockIdx.x * blockDim.x + threadIdx.x;
  if (c >= NCODES) return;
  const float4* r4 = (const float4*)(E + (size_t)c * DIM);
  float v[DIM];
  #pragma unroll
  for (int i = 0; i < 32; ++i) {
    float4 q = r4[i];
    v[4*i] = q.x; v[4*i+1] = q.y; v[4*i+2] = q.z; v[4*i+3] = q.w;
  }
  float r[8];
  #pragma unroll
  for (int j = 0; j < 8; ++j) r[j] = v[j] * v[j];
  #pragma unroll
  for (int i = 1; i < 16; ++i) {
    #pragma unroll
    for (int j = 0; j < 8; ++j) { float s = v[8*i+j] * v[8*i+j]; r[j] = r[j] + s; }
  }
  ee[c] = ((r[0]+r[1])+(r[2]+r[3])) + ((r[4]+r[5])+(r[6]+r[7]));
}

// ---------------- E -> bf16 in MFMA B-fragment layout (verified r8/r9) --------
// unit id = (ct*4 + s)*64 + l : lane l holds E[ct*16+(l&15)][s*32+(l>>4)*8+j].
__global__ __launch_bounds__(256) void ebf_kernel(const float* __restrict__ E,
                                                  unsigned short* __restrict__ ebf) {
  const int id = blockIdx.x * 256 + threadIdx.x;    // 0..16383
  const int l  = id & 63;
  const int s  = (id >> 6) & 3;
  const int ct = id >> 8;
  const int c  = ct * 16 + (l & 15);
  const int ko = s * 32 + (l >> 4) * 8;
  const float4* p = (const float4*)(E + (size_t)c * DIM + ko);
  float4 A = p[0], B = p[1];
  short8 v;
  v[0]=f2bf(A.x); v[1]=f2bf(A.y); v[2]=f2bf(A.z); v[3]=f2bf(A.w);
  v[4]=f2bf(B.x); v[5]=f2bf(B.y); v[6]=f2bf(B.z); v[7]=f2bf(B.w);
  ((short8*)ebf)[id] = v;
}

// ---------------- main: shared-E LDS GEMM, A-frags in regs, 2 blocks/CU -------
// 256 threads = 4 waves; wave wv owns token-tiles 2wv, 2wv+1 (A-frags in 32
// VGPRs). E-frags staged per 128-code tile (32KB frag-linear, double-buffered)
// -> lane-contiguous conflict-free ds_read_b128. LDS ~74KB -> 2 blocks/CU so
// block-synchronous stalls (stage drains, barriers, phase-C gather latency)
// overlap with the co-resident block's MFMA work.
// Phase A: approx min per token. Phase B: re-sweep, gather d < min+MARGIN.
// Phase C: exact f32 rescore, u64 atomicMin (sortable d | code).
__global__ __launch_bounds__(256, 2) void vq_main(
    const float* __restrict__ X, const float* __restrict__ E,
    const unsigned short* __restrict__ ebf, const float* __restrict__ ee,
    float* __restrict__ out, int* __restrict__ idxg, int* __restrict__ cnt_i) {
  #pragma clang fp contract(off)
  __shared__ __align__(16) char e_lds[2 * 32768];
  __shared__ __align__(16) char region[10240];

  const int tid  = threadIdx.x;
  const int lane = tid & 63;
  const int wv   = tid >> 6;
  const long blk = blockIdx.x;
  const float* Xb = X + (size_t)blk * BT * DIM;

  float* thrf = (float*)region;                                      // 128 f
  unsigned long long* best64 = (unsigned long long*)(region + 512);  // 128 u64
  int*      cand_n = (int*)(region + 1536);
  unsigned* cand   = (unsigned*)(region + 1540);                     // CAP

  // stage E tile CT (32 frag-units = 32KB) into buffer BUF; 8 units/wave
#define STAGE_E(CT, BUF)                                                      \
  {                                                                           \
    _Pragma("unroll")                                                         \
    for (int q = 0; q < 8; ++q) {                                             \
      const int u = wv * 8 + q;                                               \
      gchar_t* src = (gchar_t*)((const char*)ebf                              \
                      + ((size_t)(((CT) * 32 + u) * 64 + lane) << 4));        \
      lchar_t* dst = (lchar_t*)(e_lds + (BUF) * 32768 + u * 1024);            \
      __builtin_amdgcn_global_load_lds(                                       \
          (const __attribute__((address_space(1))) void*)src,                 \
          (__attribute__((address_space(3))) void*)dst, 16, 0, 0);            \
    }                                                                         \
  }

  STAGE_E(0, 0)

  // ---- A-frags: convert my 2 token-tiles straight to registers -------------
  short8 afr[2][4];
  #pragma unroll
  for (int t2 = 0; t2 < 2; ++t2) {
    const int row = (wv * 2 + t2) * 16 + (lane & 15);
    #pragma unroll
    for (int s = 0; s < 4; ++s) {
      const float4* p = (const float4*)(Xb + row * DIM + (s * 4 + (lane >> 4)) * 8);
      float4 A = p[0], B = p[1];
      short8 v;
      v[0]=f2bf(A.x); v[1]=f2bf(A.y); v[2]=f2bf(A.z); v[3]=f2bf(A.w);
      v[4]=f2bf(B.x); v[5]=f2bf(B.y); v[6]=f2bf(B.z); v[7]=f2bf(B.w);
      afr[t2][s] = v;
    }
  }

  float bv[2][4];
  #pragma unroll
  for (int t2 = 0; t2 < 2; ++t2)
    #pragma unroll
    for (int rg = 0; rg < 4; ++rg) bv[t2][rg] = __builtin_inff();

  asm volatile("s_waitcnt vmcnt(0)" ::: "memory");
  __syncthreads();

  // =========================== phase A: approx min ==========================
  for (int ctile = 0; ctile < 8; ++ctile) {
    if (ctile < 7) STAGE_E(ctile + 1, (ctile + 1) & 1)
    const char* eb = e_lds + (ctile & 1) * 32768;
    #pragma unroll 2
    for (int ct = 0; ct < 8; ++ct) {
      short8 b0 = *(const short8*)(eb + (ct * 4 + 0) * 1024 + lane * 16);
      short8 b1 = *(const short8*)(eb + (ct * 4 + 1) * 1024 + lane * 16);
      short8 b2 = *(const short8*)(eb + (ct * 4 + 2) * 1024 + lane * 16);
      short8 b3 = *(const short8*)(eb + (ct * 4 + 3) * 1024 + lane * 16);
      float eevv = ee[ctile * 128 + ct * 16 + (lane & 15)];
      #pragma unroll
      for (int t2 = 0; t2 < 2; ++t2) {
        f32x4 acc = {0.f, 0.f, 0.f, 0.f};
        acc = __builtin_amdgcn_mfma_f32_16x16x32_bf16(afr[t2][0], b0, acc, 0, 0, 0);
        acc = __builtin_amdgcn_mfma_f32_16x16x32_bf16(afr[t2][1], b1, acc, 0, 0, 0);
        acc = __builtin_amdgcn_mfma_f32_16x16x32_bf16(afr[t2][2], b2, acc, 0, 0, 0);
        acc = __builtin_amdgcn_mfma_f32_16x16x32_bf16(afr[t2][3], b3, acc, 0, 0, 0);
        #pragma unroll
        for (int rg = 0; rg < 4; ++rg) {
          float d = eevv - 2.0f * acc[rg];
          if (d < bv[t2][rg]) bv[t2][rg] = d;
        }
      }
    }
    asm volatile("s_waitcnt vmcnt(0)" ::: "memory");
    __syncthreads();
  }

  // ---- per-token threshold = min + MARGIN (16-lane shuffle min) ------------
  #pragma unroll
  for (int t2 = 0; t2 < 2; ++t2)
    #pragma unroll
    for (int rg = 0; rg < 4; ++rg) {
      float b = bv[t2][rg];
      #pragma unroll
      for (int m = 1; m < 16; m <<= 1) {
        float pb = __shfl_xor(b, m, 64);
        if (pb < b) b = pb;
      }
      if ((lane & 15) == 0)
        thrf[(wv * 2 + t2) * 16 + (lane >> 4) * 4 + rg] = b + MARGIN;
    }
  __syncthreads();
  if (tid < 128) best64[tid] = ~0ull;
  if (tid == 0) *cand_n = 0;
  __syncthreads();

  float thv[2][4];
  #pragma unroll
  for (int t2 = 0; t2 < 2; ++t2)
    #pragma unroll
    for (int rg = 0; rg < 4; ++rg)
      thv[t2][rg] = thrf[(wv * 2 + t2) * 16 + (lane >> 4) * 4 + rg];

  // =========================== phase B: gather candidates ===================
  STAGE_E(0, 0)
  asm volatile("s_waitcnt vmcnt(0)" ::: "memory");
  __syncthreads();
  for (int ctile = 0; ctile < 8; ++ctile) {
    if (ctile < 7) STAGE_E(ctile + 1, (ctile + 1) & 1)
    const char* eb = e_lds + (ctile & 1) * 32768;
    #pragma unroll 2
    for (int ct = 0; ct < 8; ++ct) {
      short8 b0 = *(const short8*)(eb + (ct * 4 + 0) * 1024 + lane * 16);
      short8 b1 = *(const short8*)(eb + (ct * 4 + 1) * 1024 + lane * 16);
      short8 b2 = *(const short8*)(eb + (ct * 4 + 2) * 1024 + lane * 16);
      short8 b3 = *(const short8*)(eb + (ct * 4 + 3) * 1024 + lane * 16);
      float eevv = ee[ctile * 128 + ct * 16 + (lane & 15)];
      const int code = ctile * 128 + ct * 16 + (lane & 15);
      #pragma unroll
      for (int t2 = 0; t2 < 2; ++t2) {
        f32x4 acc = {0.f, 0.f, 0.f, 0.f};
        acc = __builtin_amdgcn_mfma_f32_16x16x32_bf16(afr[t2][0], b0, acc, 0, 0, 0);
        acc = __builtin_amdgcn_mfma_f32_16x16x32_bf16(afr[t2][1], b1, acc, 0, 0, 0);
        acc = __builtin_amdgcn_mfma_f32_16x16x32_bf16(afr[t2][2], b2, acc, 0, 0, 0);
        acc = __builtin_amdgcn_mfma_f32_16x16x32_bf16(afr[t2][3], b3, acc, 0, 0, 0);
        #pragma unroll
        for (int rg = 0; rg < 4; ++rg) {
          float d = eevv - 2.0f * acc[rg];
          if (d < thv[t2][rg]) {
            int slot = atomicAdd(cand_n, 1);
            if (slot < CAP) {
              const int token = (wv * 2 + t2) * 16 + (lane >> 4) * 4 + rg;
              cand[slot] = ((unsigned)token << 10) | (unsigned)code;
            }
          }
        }
      }
    }
    asm volatile("s_waitcnt vmcnt(0)" ::: "memory");
    __syncthreads();
  }
  __syncthreads();

  // =========================== phase C: exact rescore =======================
  {
    int cn = *cand_n;
    const int nc = cn < CAP ? cn : CAP;
    for (int i = tid; i < nc; i += 256) {
      const unsigned pc = cand[i];
      const int t = pc >> 10, c = pc & 1023;
      const float* xr = Xb + t * DIM;
      const float* er = E + (size_t)c * DIM;
      float dot = 0.0f;
      #pragma unroll
      for (int k = 0; k < DIM; ++k) dot = __builtin_fmaf(xr[k], er[k], dot);
      float d = ee[c] - 2.0f * dot;
      unsigned u = __float_as_uint(d);
      u ^= (unsigned)((int)u >> 31) | 0x80000000u;     // sortable float key
      unsigned long long key = ((unsigned long long)u << 32) | (unsigned)c;
      atomicMin(best64 + t, key);
    }
  }
  __syncthreads();

  // ---- epilogue: idx + histogram + out = x + (e - x) -----------------------
  if (tid < BT) {
    const int c0 = (int)(best64[tid] & 1023ull);
    idxg[blk * BT + tid] = c0;
    atomicAdd(cnt_i + c0, 1);
  }
  const int tt2 = tid >> 1, hf = tid & 1;
  const int fi2 = (int)(best64[tt2] & 1023ull);
  const float* xrow = Xb  + tt2 * DIM + hf * 64;
  const float* erow = E   + ((size_t)fi2 << 7) + hf * 64;
  float*       orow = out + ((size_t)blk * BT + tt2) * DIM + hf * 64;
  #pragma unroll
  for (int q = 0; q < 16; ++q) {
    float4 xv = *(const float4*)(xrow + q * 4);
    float4 ev = *(const float4*)(erow + q * 4);
    float4 o;
    o.x = xv.x + (ev.x - xv.x);
    o.y = xv.y + (ev.y - xv.y);
    o.z = xv.z + (ev.z - xv.z);
    o.w = xv.w + (ev.w - xv.w);
    *(float4*)(orow + q * 4) = o;
  }
}

// ---------------- prefix + finalize1: cs outputs, cs_ws, CSR offsets ----------
__global__ __launch_bounds__(1024) void prefix_fin1(
    const float* __restrict__ cluster_size, const int* __restrict__ cnt_i,
    float* __restrict__ out_cs, float* __restrict__ cs_ws,
    int* __restrict__ cursor, int* __restrict__ offs) {
  #pragma clang fp contract(off)
  __shared__ float red[1024];
  __shared__ int   sc[1024];
  const int n = threadIdx.x;
  const int cnt = cnt_i[n];
  float ncs = 0.99f * cluster_size[n] + 0.01f * (float)cnt;
  out_cs[n] = ncs;
  red[n] = ncs;
  sc[n]  = cnt;
  __syncthreads();
  for (int s = 512; s > 0; s >>= 1) {
    if (n < s) red[n] = red[n] + red[n + s];
    __syncthreads();
  }
  float ntot = red[0];
  cs_ws[n] = (ncs + 1e-5f) / (ntot + 0.01024f) * ntot;
  for (int d = 1; d < 1024; d <<= 1) {
    int t = (n >= d) ? sc[n - d] : 0;
    __syncthreads();
    sc[n] += t;
    __syncthreads();
  }
  int excl = sc[n] - cnt;
  cursor[n] = excl;
  offs[n]   = excl;
}

// ---------------- scatter tokens into CSR order -------------------------------
__global__ __launch_bounds__(256) void scatter_kernel(
    const int* __restrict__ idxg, int* __restrict__ cursor,
    int* __restrict__ order) {
  const int t  = blockIdx.x * 256 + threadIdx.x;
  const int fi = idxg[t];
  const int slot = atomicAdd(cursor + fi, 1);
  order[slot] = t;
}

// ---------------- sums: fixed 64-entry CSR chunks per wave, MLP-friendly ------
__global__ __launch_bounds__(256) void sums_chunk(
    const float* __restrict__ X, const int* __restrict__ order,
    const int* __restrict__ idxg, float* __restrict__ sums) {
  #pragma clang fp contract(off)
  const int lane = threadIdx.x & 63;
  const int base = blockIdx.x * 256 + (threadIdx.x >> 6) * 64;
  const int tl = order[base + lane];
  const int cl = idxg[tl];
  float ax = 0.f, ay = 0.f;
  int cprev = __shfl(cl, 0, 64);
  #pragma unroll
  for (int j0 = 0; j0 < 64; j0 += 8) {
    int tj[8], cj[8];
    float2 buf[8];
    #pragma unroll
    for (int q = 0; q < 8; ++q) tj[q] = __shfl(tl, j0 + q, 64);
    #pragma unroll
    for (int q = 0; q < 8; ++q)
      buf[q] = *((const float2*)(X + ((size_t)tj[q] << 7)) + lane);
    #pragma unroll
    for (int q = 0; q < 8; ++q) cj[q] = __shfl(cl, j0 + q, 64);
    #pragma unroll
    for (int q = 0; q < 8; ++q) {
      if (cj[q] != cprev) {                       // wave-uniform branch
        atomicAdd(sums + cprev * DIM + lane * 2,     ax);
        atomicAdd(sums + cprev * DIM + lane * 2 + 1, ay);
        ax = 0.f; ay = 0.f; cprev = cj[q];
      }
      ax = ax + buf[q].x;
      ay = ay + buf[q].y;
    }
  }
  atomicAdd(sums + cprev * DIM + lane * 2,     ax);
  atomicAdd(sums + cprev * DIM + lane * 2 + 1, ay);
}

// ---------------- finalize2: EMA + divide -------------------------------------
__global__ __launch_bounds__(256) void finalize2(
    const float* __restrict__ embed_avg, const float* __restrict__ sums,
    const float* __restrict__ cs_ws, float* __restrict__ out_embed,
    float* __restrict__ out_avg) {
  #pragma clang fp contract(off)
  int i = blockIdx.x * 256 + threadIdx.x;
  float av = 0.99f * embed_avg[i] + 0.01f * sums[i];
  out_avg[i]   = av;
  out_embed[i] = av / cs_ws[i >> 7];
}

extern "C" void kernel_launch(void* const* d_in, const int* in_sizes, int n_in,
                              void* d_out, int out_size, void* d_ws, size_t ws_size,
                              hipStream_t stream) {
  const float* X  = (const float*)d_in[0];
  const float* E  = (const float*)d_in[1];
  const float* CS = (const float*)d_in[2];
  const float* EA = (const float*)d_in[3];
  float* out = (float*)d_out;
  float* ws  = (float*)d_ws;

  int*   cnt_i  = (int*)ws;                  // 1024 i   } zeroed together
  float* sums   = ws + 1024;                 // 131072 f }
  float* eearr  = ws + 132096;               // 1024 f
  float* csarr  = ws + 133120;               // 1024 f
  int*   cursor = (int*)(ws + 134144);       // 1024 i
  int*   offs   = (int*)(ws + 135168);       // 1024 i
  int*   idxarr = (int*)(ws + 136192);       // 65536 i
  int*   order  = (int*)(ws + 201728);       // 65536 i
  unsigned short* ebf = (unsigned short*)(ws + 267264);  // 256 KB bf16 frags

  hipMemsetAsync(d_ws, 0, 132096 * sizeof(float), stream);

  ee_kernel     <<<NCODES / 256, 256, 0, stream>>>(E, eearr);
  ebf_kernel    <<<64,           256, 0, stream>>>(E, ebf);
  vq_main       <<<NTOK / BT,    256, 0, stream>>>(X, E, ebf, eearr, out,
                                                   idxarr, cnt_i);
  prefix_fin1   <<<1, 1024, 0, stream>>>(CS, cnt_i, out + 8519680, csarr,
                                         cursor, offs);
  scatter_kernel<<<NTOK / 256,   256, 0, stream>>>(idxarr, cursor, order);
  sums_chunk    <<<NTOK / 256,   256, 0, stream>>>(X, order, idxarr, sums);
  finalize2     <<<131072 / 256, 256, 0, stream>>>(EA, sums, csarr,
                                                   out + 8388608, out + 8520704);
}

// Round 11
// 164.975 us; speedup vs baseline: 9.6718x; 1.0486x over previous
//
#include <hip/hip_runtime.h>

#define NTOK   65536
#define NCODES 1024
#define DIM    128
#define BT     128          // tokens per block
#define MARGIN 6.0f
#define CAP    2047

typedef __attribute__((ext_vector_type(8))) short short8;
typedef __attribute__((ext_vector_type(4))) float f32x4;

__device__ __forceinline__ unsigned short f2bf(float f) {
  unsigned u = __float_as_uint(f);
  u += 0x7FFFu + ((u >> 16) & 1u);          // RTNE
  return (unsigned short)(u >> 16);
}

// ---------------- prep: ebf (E -> bf16 B-frags, verified r8-r10) + ee ---------
// blocks 0..63: ebf units; blocks 64..67: ee rows (numpy pairwise 8-acc order).
__global__ __launch_bounds__(256) void prep_kernel(const float* __restrict__ E,
                                                   float* __restrict__ ee,
                                                   unsigned short* __restrict__ ebf) {
  #pragma clang fp contract(off)
  const int b = blockIdx.x;
  if (b < 64) {
    const int id = b * 256 + threadIdx.x;    // 0..16383
    const int l  = id & 63;
    const int s  = (id >> 6) & 3;
    const int ct = id >> 8;
    const int c  = ct * 16 + (l & 15);
    const int ko = s * 32 + (l >> 4) * 8;
    const float4* p = (const float4*)(E + (size_t)c * DIM + ko);
    float4 A = p[0], B = p[1];
    short8 v;
    v[0]=f2bf(A.x); v[1]=f2bf(A.y); v[2]=f2bf(A.z); v[3]=f2bf(A.w);
    v[4]=f2bf(B.x); v[5]=f2bf(B.y); v[6]=f2bf(B.z); v[7]=f2bf(B.w);
    ((short8*)ebf)[id] = v;
  } else {
    const int c = (b - 64) * 256 + threadIdx.x;   // 0..1023
    const float4* r4 = (const float4*)(E + (size_t)c * DIM);
    float v[DIM];
    #pragma unroll
    for (int i = 0; i < 32; ++i) {
      float4 q = r4[i];
      v[4*i] = q.x; v[4*i+1] = q.y; v[4*i+2] = q.z; v[4*i+3] = q.w;
    }
    float r[8];
    #pragma unroll
    for (int j = 0; j < 8; ++j) r[j] = v[j] * v[j];
    #pragma unroll
    for (int i = 1; i < 16; ++i) {
      #pragma unroll
      for (int j = 0; j < 8; ++j) { float s = v[8*i+j] * v[8*i+j]; r[j] = r[j] + s; }
    }
    ee[c] = ((r[0]+r[1])+(r[2]+r[3])) + ((r[4]+r[5])+(r[6]+r[7]));
  }
}

// ---------------- main: B-frags in REGISTERS, A-frags from LDS ----------------
// 256 threads = 4 waves, __launch_bounds__(256,2) -> 256-VGPR cap, 2 blocks/CU.
// Wave holds bfr[8][4] (128 VGPR) = one 128-code set; sweeps 2 sets per phase
// with an L2 reload between. Per tt: 4 ds_read_b128 feed 32 MFMA (4x the
// MFMA/LDS-read ratio of r10). X staged once as bf16 A-frags in LDS (32KB).
// Phase A: approx min per token (bestA cross-wave merge). Phase B: emit
// cands d < min+MARGIN (set1 first - still resident). Phase C: exact f32
// rescore, u64 atomicMin (sortable d | code) -> lowest-index-tie argmin.
__global__ __launch_bounds__(256, 2) void vq_main(
    const float* __restrict__ X, const float* __restrict__ E,
    const unsigned short* __restrict__ ebf, const float* __restrict__ ee,
    float* __restrict__ out, int* __restrict__ idxg, int* __restrict__ cnt_i) {
  #pragma clang fp contract(off)
  __shared__ __align__(16) char x_lds[32768];
  __shared__ float bestA[4][BT];
  __shared__ float thrf[BT];
  __shared__ unsigned long long best64[BT];
  __shared__ int cand_n;
  __shared__ unsigned cand[CAP];

  const int tid  = threadIdx.x;
  const int lane = tid & 63;
  const int wv   = tid >> 6;
  const long blk = blockIdx.x;
  const float* Xb = X + (size_t)blk * BT * DIM;

  // ---- stage X -> bf16 A-frag layout (transpose of ebf unit layout) --------
  {
    const int r = tid >> 1, h = tid & 1;
    const float4* p4 = (const float4*)(Xb + r * DIM + h * 64);
    #pragma unroll
    for (int q = 0; q < 8; ++q) {
      float4 A = p4[2*q], B = p4[2*q+1];
      short8 v;
      v[0]=f2bf(A.x); v[1]=f2bf(A.y); v[2]=f2bf(A.z); v[3]=f2bf(A.w);
      v[4]=f2bf(B.x); v[5]=f2bf(B.y); v[6]=f2bf(B.z); v[7]=f2bf(B.w);
      const int o    = h * 8 + q;
      const int unit = (r >> 4) * 4 + (o >> 2);
      const int ln   = ((o & 3) << 4) | (r & 15);
      *(short8*)(x_lds + unit * 1024 + ln * 16) = v;
    }
  }

  short8 bfr[8][4];
  float  eev[8];
  const short8* ebv = (const short8*)ebf;

#define LOAD_SET(SET)                                                         \
  { _Pragma("unroll")                                                         \
    for (int ct = 0; ct < 8; ++ct) {                                          \
      _Pragma("unroll")                                                       \
      for (int s = 0; s < 4; ++s)                                             \
        bfr[ct][s] = ebv[(((SET) * 32 + wv * 8 + ct) * 4 + s) * 64 + lane];   \
      eev[ct] = ee[(SET) * 512 + wv * 128 + ct * 16 + (lane & 15)];           \
    } }

#define MFMA4(ACC, A0, A1, A2, A3, CT)                                        \
  ACC = __builtin_amdgcn_mfma_f32_16x16x32_bf16(A0, bfr[CT][0], ACC, 0, 0, 0);\
  ACC = __builtin_amdgcn_mfma_f32_16x16x32_bf16(A1, bfr[CT][1], ACC, 0, 0, 0);\
  ACC = __builtin_amdgcn_mfma_f32_16x16x32_bf16(A2, bfr[CT][2], ACC, 0, 0, 0);\
  ACC = __builtin_amdgcn_mfma_f32_16x16x32_bf16(A3, bfr[CT][3], ACC, 0, 0, 0);

#define SWEEP_MIN(FIRST)                                                      \
  for (int tt = 0; tt < 8; ++tt) {                                            \
    const char* xb = x_lds + tt * 4096 + lane * 16;                           \
    short8 a0 = *(const short8*)(xb);                                         \
    short8 a1 = *(const short8*)(xb + 1024);                                  \
    short8 a2 = *(const short8*)(xb + 2048);                                  \
    short8 a3 = *(const short8*)(xb + 3072);                                  \
    float bv0 = __builtin_inff(), bv1 = __builtin_inff();                     \
    float bv2 = __builtin_inff(), bv3 = __builtin_inff();                     \
    _Pragma("unroll")                                                         \
    for (int ct = 0; ct < 8; ++ct) {                                          \
      f32x4 acc = {0.f, 0.f, 0.f, 0.f};                                       \
      MFMA4(acc, a0, a1, a2, a3, ct)                                          \
      float d0 = eev[ct] - 2.0f * acc[0]; if (d0 < bv0) bv0 = d0;             \
      float d1 = eev[ct] - 2.0f * acc[1]; if (d1 < bv1) bv1 = d1;             \
      float d2 = eev[ct] - 2.0f * acc[2]; if (d2 < bv2) bv2 = d2;             \
      float d3 = eev[ct] - 2.0f * acc[3]; if (d3 < bv3) bv3 = d3;             \
    }                                                                         \
    _Pragma("unroll")                                                         \
    for (int m = 1; m < 16; m <<= 1) {                                        \
      float p0 = __shfl_xor(bv0, m, 64); if (p0 < bv0) bv0 = p0;              \
      float p1 = __shfl_xor(bv1, m, 64); if (p1 < bv1) bv1 = p1;              \
      float p2 = __shfl_xor(bv2, m, 64); if (p2 < bv2) bv2 = p2;              \
      float p3 = __shfl_xor(bv3, m, 64); if (p3 < bv3) bv3 = p3;              \
    }                                                                         \
    if ((lane & 15) == 0) {                                                   \
      const int tok = tt * 16 + (lane >> 4) * 4;                              \
      if (FIRST) {                                                            \
        bestA[wv][tok]     = bv0; bestA[wv][tok + 1] = bv1;                   \
        bestA[wv][tok + 2] = bv2; bestA[wv][tok + 3] = bv3;                   \
      } else {                                                                \
        if (bv0 < bestA[wv][tok])     bestA[wv][tok]     = bv0;               \
        if (bv1 < bestA[wv][tok + 1]) bestA[wv][tok + 1] = bv1;               \
        if (bv2 < bestA[wv][tok + 2]) bestA[wv][tok + 2] = bv2;               \
        if (bv3 < bestA[wv][tok + 3]) bestA[wv][tok + 3] = bv3;               \
      }                                                                       \
    }                                                                         \
  }

#define EMIT(D, RG, TH, CODE, TT)                                             \
  if ((D) < (TH)) {                                                           \
    int sl = atomicAdd(&cand_n, 1);                                           \
    if (sl < CAP)                                                             \
      cand[sl] = ((unsigned)((TT) * 16 + (lane >> 4) * 4 + (RG)) << 10)       \
               | (unsigned)(CODE);                                            \
  }

#define SWEEP_EMIT(CB)                                                        \
  for (int tt = 0; tt < 8; ++tt) {                                            \
    const char* xb = x_lds + tt * 4096 + lane * 16;                           \
    short8 a0 = *(const short8*)(xb);                                         \
    short8 a1 = *(const short8*)(xb + 1024);                                  \
    short8 a2 = *(const short8*)(xb + 2048);                                  \
    short8 a3 = *(const short8*)(xb + 3072);                                  \
    const float4 th4 = *(const float4*)(thrf + tt * 16 + (lane >> 4) * 4);    \
    _Pragma("unroll")                                                         \
    for (int ct = 0; ct < 8; ++ct) {                                          \
      f32x4 acc = {0.f, 0.f, 0.f, 0.f};                                       \
      MFMA4(acc, a0, a1, a2, a3, ct)                                          \
      const int code = (CB) + ct * 16 + (lane & 15);                          \
      float d0 = eev[ct] - 2.0f * acc[0]; EMIT(d0, 0, th4.x, code, tt)        \
      float d1 = eev[ct] - 2.0f * acc[1]; EMIT(d1, 1, th4.y, code, tt)        \
      float d2 = eev[ct] - 2.0f * acc[2]; EMIT(d2, 2, th4.z, code, tt)        \
      float d3 = eev[ct] - 2.0f * acc[3]; EMIT(d3, 3, th4.w, code, tt)        \
    }                                                                         \
  }

  LOAD_SET(0)
  __syncthreads();                      // x_lds ready

  // =========================== phase A: approx min ==========================
  SWEEP_MIN(1)
  LOAD_SET(1)
  SWEEP_MIN(0)
  __syncthreads();                      // bestA complete

  if (tid < BT) {
    float m0 = bestA[0][tid], m1 = bestA[1][tid];
    float m2 = bestA[2][tid], m3 = bestA[3][tid];
    float mm = fminf(fminf(m0, m1), fminf(m2, m3));
    thrf[tid]   = mm + MARGIN;
    best64[tid] = ~0ull;
  }
  if (tid == 0) cand_n = 0;
  __syncthreads();

  // =========================== phase B: gather candidates ===================
  SWEEP_EMIT(512 + wv * 128)            // set 1 still in registers
  LOAD_SET(0)
  SWEEP_EMIT(wv * 128)
  __syncthreads();

  // =========================== phase C: exact rescore =======================
  {
    int cn = cand_n;
    const int nc = cn < CAP ? cn : CAP;
    for (int i = tid; i < nc; i += 256) {
      const unsigned pc = cand[i];
      const int t = pc >> 10, c = pc & 1023;
      const float* xr = Xb + t * DIM;
      const float* er = E + (size_t)c * DIM;
      float dot = 0.0f;
      #pragma unroll
      for (int k = 0; k < DIM; ++k) dot = __builtin_fmaf(xr[k], er[k], dot);
      float d = ee[c] - 2.0f * dot;
      unsigned u = __float_as_uint(d);
      u ^= (unsigned)((int)u >> 31) | 0x80000000u;     // sortable float key
      unsigned long long key = ((unsigned long long)u << 32) | (unsigned)c;
      atomicMin(best64 + t, key);
    }
  }
  __syncthreads();

  // ---- epilogue: idx + histogram + out = x + (e - x) -----------------------
  if (tid < BT) {
    const int c0 = (int)(best64[tid] & 1023ull);
    idxg[blk * BT + tid] = c0;
    atomicAdd(cnt_i + c0, 1);
  }
  const int tt2 = tid >> 1, hf = tid & 1;
  const int fi2 = (int)(best64[tt2] & 1023ull);
  const float* xrow = Xb  + tt2 * DIM + hf * 64;
  const float* erow = E   + ((size_t)fi2 << 7) + hf * 64;
  float*       orow = out + ((size_t)blk * BT + tt2) * DIM + hf * 64;
  #pragma unroll
  for (int q = 0; q < 16; ++q) {
    float4 xv = *(const float4*)(xrow + q * 4);
    float4 ev = *(const float4*)(erow + q * 4);
    float4 o;
    o.x = xv.x + (ev.x - xv.x);
    o.y = xv.y + (ev.y - xv.y);
    o.z = xv.z + (ev.z - xv.z);
    o.w = xv.w + (ev.w - xv.w);
    *(float4*)(orow + q * 4) = o;
  }
}

// ---------------- prefix + finalize1: cs outputs, cs_ws, CSR offsets ----------
__global__ __launch_bounds__(1024) void prefix_fin1(
    const float* __restrict__ cluster_size, const int* __restrict__ cnt_i,
    float* __restrict__ out_cs, float* __restrict__ cs_ws,
    int* __restrict__ cursor, int* __restrict__ offs) {
  #pragma clang fp contract(off)
  __shared__ float red[1024];
  __shared__ int   sc[1024];
  const int n = threadIdx.x;
  const int cnt = cnt_i[n];
  float ncs = 0.99f * cluster_size[n] + 0.01f * (float)cnt;
  out_cs[n] = ncs;
  red[n] = ncs;
  sc[n]  = cnt;
  __syncthreads();
  for (int s = 512; s > 0; s >>= 1) {
    if (n < s) red[n] = red[n] + red[n + s];
    __syncthreads();
  }
  float ntot = red[0];
  cs_ws[n] = (ncs + 1e-5f) / (ntot + 0.01024f) * ntot;
  for (int d = 1; d < 1024; d <<= 1) {
    int t = (n >= d) ? sc[n - d] : 0;
    __syncthreads();
    sc[n] += t;
    __syncthreads();
  }
  int excl = sc[n] - cnt;
  cursor[n] = excl;
  offs[n]   = excl;
}

// ---------------- scatter tokens into CSR order -------------------------------
__global__ __launch_bounds__(256) void scatter_kernel(
    const int* __restrict__ idxg, int* __restrict__ cursor,
    int* __restrict__ order) {
  const int t  = blockIdx.x * 256 + threadIdx.x;
  const int fi = idxg[t];
  const int slot = atomicAdd(cursor + fi, 1);
  order[slot] = t;
}

// ---------------- sums: fixed 64-entry CSR chunks per wave, MLP-friendly ------
__global__ __launch_bounds__(256) void sums_chunk(
    const float* __restrict__ X, const int* __restrict__ order,
    const int* __restrict__ idxg, float* __restrict__ sums) {
  #pragma clang fp contract(off)
  const int lane = threadIdx.x & 63;
  const int base = blockIdx.x * 256 + (threadIdx.x >> 6) * 64;
  const int tl = order[base + lane];
  const int cl = idxg[tl];
  float ax = 0.f, ay = 0.f;
  int cprev = __shfl(cl, 0, 64);
  #pragma unroll
  for (int j0 = 0; j0 < 64; j0 += 8) {
    int tj[8], cj[8];
    float2 buf[8];
    #pragma unroll
    for (int q = 0; q < 8; ++q) tj[q] = __shfl(tl, j0 + q, 64);
    #pragma unroll
    for (int q = 0; q < 8; ++q)
      buf[q] = *((const float2*)(X + ((size_t)tj[q] << 7)) + lane);
    #pragma unroll
    for (int q = 0; q < 8; ++q) cj[q] = __shfl(cl, j0 + q, 64);
    #pragma unroll
    for (int q = 0; q < 8; ++q) {
      if (cj[q] != cprev) {                       // wave-uniform branch
        atomicAdd(sums + cprev * DIM + lane * 2,     ax);
        atomicAdd(sums + cprev * DIM + lane * 2 + 1, ay);
        ax = 0.f; ay = 0.f; cprev = cj[q];
      }
      ax = ax + buf[q].x;
      ay = ay + buf[q].y;
    }
  }
  atomicAdd(sums + cprev * DIM + lane * 2,     ax);
  atomicAdd(sums + cprev * DIM + lane * 2 + 1, ay);
}

// ---------------- finalize2: EMA + divide -------------------------------------
__global__ __launch_bounds__(256) void finalize2(
    const float* __restrict__ embed_avg, const float* __restrict__ sums,
    const float* __restrict__ cs_ws, float* __restrict__ out_embed,
    float* __restrict__ out_avg) {
  #pragma clang fp contract(off)
  int i = blockIdx.x * 256 + threadIdx.x;
  float av = 0.99f * embed_avg[i] + 0.01f * sums[i];
  out_avg[i]   = av;
  out_embed[i] = av / cs_ws[i >> 7];
}

extern "C" void kernel_launch(void* const* d_in, const int* in_sizes, int n_in,
                              void* d_out, int out_size, void* d_ws, size_t ws_size,
                              hipStream_t stream) {
  const float* X  = (const float*)d_in[0];
  const float* E  = (const float*)d_in[1];
  const float* CS = (const float*)d_in[2];
  const float* EA = (const float*)d_in[3];
  float* out = (float*)d_out;
  float* ws  = (float*)d_ws;

  int*   cnt_i  = (int*)ws;                  // 1024 i   } zeroed together
  float* sums   = ws + 1024;                 // 131072 f }
  float* eearr  = ws + 132096;               // 1024 f
  float* csarr  = ws + 133120;               // 1024 f
  int*   cursor = (int*)(ws + 134144);       // 1024 i
  int*   offs   = (int*)(ws + 135168);       // 1024 i
  int*   idxarr = (int*)(ws + 136192);       // 65536 i
  int*   order  = (int*)(ws + 201728);       // 65536 i
  unsigned short* ebf = (unsigned short*)(ws + 267264);  // 256 KB bf16 frags

  hipMemsetAsync(d_ws, 0, 132096 * sizeof(float), stream);

  prep_kernel   <<<68,           256, 0, stream>>>(E, eearr, ebf);
  vq_main       <<<NTOK / BT,    256, 0, stream>>>(X, E, ebf, eearr, out,
                                                   idxarr, cnt_i);
  prefix_fin1   <<<1, 1024, 0, stream>>>(CS, cnt_i, out + 8519680, csarr,
                                         cursor, offs);
  scatter_kernel<<<NTOK / 256,   256, 0, stream>>>(idxarr, cursor, order);
  sums_chunk    <<<NTOK / 256,   256, 0, stream>>>(X, order, idxarr, sums);
  finalize2     <<<131072 / 256, 256, 0, stream>>>(EA, sums, csarr,
                                                   out + 8388608, out + 8520704);
}